// Round 5
// baseline (472.843 us; speedup 1.0000x reference)
//
#include <hip/hip_runtime.h>
#include <hip/hip_bf16.h>
#include <math.h>

#define NB 32          // graphs
#define N_PER 1000
#define TOTALN 32000
#define NE 512000
#define HID 128
#define Dh 64
#define NH 3
#define EPSV 1e-6f
#define PCH 25         // pool chunks per graph (40 nodes each)
#define W1CH 500       // k_w1 chunks (2 n's each)

__device__ __forceinline__ float softplusf(float x) {
    return fmaxf(x, 0.0f) + log1pf(expf(-fabsf(x)));
}

__global__ __launch_bounds__(256) void k_init_deg(float* deg) {
    int i = blockIdx.x * 256 + threadIdx.x;
    if (i < TOTALN) deg[i] = 1.0f;   // self loop
}

__global__ __launch_bounds__(256) void k_deg(const int* __restrict__ ei, float* deg) {
    int e = blockIdx.x * 256 + threadIdx.x;
    if (e < NE) atomicAdd(&deg[ei[NE + e]], 1.0f);
}

// dinv = rsqrt(deg); cnt = (int)deg - 1 (edges only, self-loop excluded)
__global__ __launch_bounds__(256) void k_prep(float* __restrict__ d, int* __restrict__ cnt) {
    int i = blockIdx.x * 256 + threadIdx.x;
    if (i < TOTALN) {
        float v = d[i];
        cnt[i] = (int)v - 1;
        d[i] = rsqrtf(v);
    }
}

// exclusive scan of cnt[32000] -> rowptr; 125 blocks x 256
__global__ __launch_bounds__(256) void k_scan_block(const int* __restrict__ cnt,
                                                    int* __restrict__ rowptr,
                                                    int* __restrict__ bsum) {
    __shared__ int sh[256];
    int t = threadIdx.x;
    int i = blockIdx.x * 256 + t;
    int v = cnt[i];
    sh[t] = v;
    __syncthreads();
    for (int off = 1; off < 256; off <<= 1) {
        int add = (t >= off) ? sh[t - off] : 0;
        __syncthreads();
        sh[t] += add;
        __syncthreads();
    }
    rowptr[i] = sh[t] - v;   // exclusive within block
    if (t == 255) bsum[blockIdx.x] = sh[255];
}

__global__ void k_scan_tot(int* __restrict__ bsum) {
    if (threadIdx.x == 0) {
        int run = 0;
        for (int i = 0; i < 125; ++i) { int t = bsum[i]; bsum[i] = run; run += t; }
    }
}

__global__ __launch_bounds__(256) void k_scan_add(int* __restrict__ rowptr,
                                                  const int* __restrict__ bsum,
                                                  int* __restrict__ cursor) {
    int i = blockIdx.x * 256 + threadIdx.x;
    int v = rowptr[i] + bsum[blockIdx.x];
    rowptr[i] = v;
    cursor[i] = v;
    if (i == 0) rowptr[TOTALN] = NE;
}

__global__ __launch_bounds__(256) void k_fill(const int* __restrict__ ei,
                                              const float* __restrict__ dinv,
                                              int* __restrict__ cursor,
                                              int* __restrict__ csr_src,
                                              float* __restrict__ csr_w) {
    int e = blockIdx.x * 256 + threadIdx.x;
    if (e < NE) {
        int s = ei[e], d = ei[NE + e];
        int pos = atomicAdd(&cursor[d], 1);
        csr_src[pos] = s;
        csr_w[pos] = dinv[s] * dinv[d];
    }
}

// Y[rows x 128] = X[rows x 128] @ W[128 x 128]; 64 rows per block
__global__ __launch_bounds__(256) void k_mm128(const float* __restrict__ X,
                                               const float* __restrict__ W,
                                               float* __restrict__ Y) {
    __shared__ float xs[64][128];
    __shared__ float ws[32][128];
    int tid = threadIdx.x;
    int row0 = blockIdx.x * 64;
    int c = tid & 127, rp = tid >> 7;
    for (int i = 0; i < 32; ++i) {
        int idx = tid + i * 256;
        xs[idx >> 7][idx & 127] = X[(row0 + (idx >> 7)) * 128 + (idx & 127)];
    }
    float acc[32];
#pragma unroll
    for (int i = 0; i < 32; ++i) acc[i] = 0.f;
    for (int kc = 0; kc < 4; ++kc) {
        __syncthreads();
        for (int i = 0; i < 16; ++i) {
            int idx = tid + i * 256;
            ws[idx >> 7][idx & 127] = W[(kc * 32 + (idx >> 7)) * 128 + (idx & 127)];
        }
        __syncthreads();
#pragma unroll 4
        for (int k = 0; k < 32; ++k) {
            float w = ws[k][c];
#pragma unroll
            for (int i = 0; i < 32; ++i)
                acc[i] += xs[rp * 32 + i][kc * 32 + k] * w;
        }
    }
#pragma unroll
    for (int i = 0; i < 32; ++i)
        Y[(row0 + rp * 32 + i) * 128 + c] = acc[i];
}

// CSR gather: 1 wave per node, float2 per lane, 4-deep edge ILP.
// MODE 0: +bias,relu ; MODE 1: plain
template<int MODE>
__global__ __launch_bounds__(256) void k_gather(const float* __restrict__ feat,
                                                float* __restrict__ out,
                                                const int* __restrict__ rowptr,
                                                const int* __restrict__ csr_src,
                                                const float* __restrict__ csr_w,
                                                const float* __restrict__ dinv,
                                                const float* __restrict__ bias) {
    int wid = threadIdx.x >> 6, lane = threadIdx.x & 63;
    int v = blockIdx.x * 4 + wid;
    const float2* f2 = (const float2*)feat;
    float dv = dinv[v];
    float2 self = f2[v * 64 + lane];
    float acc0 = self.x * dv * dv, acc1 = self.y * dv * dv;
    int e = rowptr[v], e1 = rowptr[v + 1];
    for (; e + 4 <= e1; e += 4) {
        int s0 = csr_src[e], s1 = csr_src[e + 1], s2 = csr_src[e + 2], s3 = csr_src[e + 3];
        float w0 = csr_w[e], w1 = csr_w[e + 1], w2 = csr_w[e + 2], w3 = csr_w[e + 3];
        float2 f0 = f2[s0 * 64 + lane];
        float2 f1 = f2[s1 * 64 + lane];
        float2 fa = f2[s2 * 64 + lane];
        float2 fb = f2[s3 * 64 + lane];
        acc0 += f0.x * w0 + f1.x * w1 + fa.x * w2 + fb.x * w3;
        acc1 += f0.y * w0 + f1.y * w1 + fa.y * w2 + fb.y * w3;
    }
    for (; e < e1; ++e) {
        int s = csr_src[e];
        float w = csr_w[e];
        float2 f = f2[s * 64 + lane];
        acc0 += f.x * w;
        acc1 += f.y * w;
    }
    if (MODE == 0) {
        int c = lane * 2;
        acc0 = fmaxf(acc0 + bias[c], 0.f);
        acc1 = fmaxf(acc1 + bias[c + 1], 0.f);
    }
    ((float2*)out)[v * 64 + lane] = make_float2(acc0, acc1);
}

// pool stage 1: block = (graph b, chunk of 40 nodes) -> partial sums
__global__ __launch_bounds__(256) void k_pool1(const float* __restrict__ A,
                                               float* __restrict__ pp) {
    __shared__ float sh[256];
    int b = blockIdx.x / PCH, ch = blockIdx.x % PCH;
    int c = threadIdx.x & 127, half = threadIdx.x >> 7;
    float acc = 0.f;
    int n0 = ch * 40;
#pragma unroll 4
    for (int j = half; j < 40; j += 2)
        acc += A[(b * N_PER + n0 + j) * 128 + c];
    sh[threadIdx.x] = acc;
    __syncthreads();
    if (threadIdx.x < 128)
        pp[blockIdx.x * 128 + c] = sh[c] + sh[128 + c];
}

// pool stage 2: reduce 25 partials, apply mean + layer-3 bias
__global__ __launch_bounds__(256) void k_pool2(const float* __restrict__ pp,
                                               const float* __restrict__ bias,
                                               float* __restrict__ hg) {
    int i = blockIdx.x * 256 + threadIdx.x;   // b*128 + c
    if (i >= NB * 128) return;
    int b = i >> 7, c = i & 127;
    float s = 0.f;
#pragma unroll
    for (int ch = 0; ch < PCH; ++ch)
        s += pp[(b * PCH + ch) * 128 + c];
    hg[i] = s * (1.0f / N_PER) + bias[c];
}

// k_w1: block = (head h, chunk of 2 n's); 4 waves = (nsub, b-half).
// Each wave: full k=128 dot for 16 graphs, one n, lane = d.
// Wg1 read directly (coalesced 256B/wave/k, 2-stage pipelined);
// hg via wave-uniform loads. Partials p1[chunk][h][b][d] (n-summed via LDS).
__global__ __launch_bounds__(256) void k_w1(const float* __restrict__ hg,
                                            const float* __restrict__ Wg1,
                                            const float* __restrict__ bg1,
                                            const float* __restrict__ actions,
                                            float* __restrict__ p1) {
    __shared__ float red[32][64];
    int h = blockIdx.x / W1CH, chunk = blockIdx.x % W1CH;
    int tid = threadIdx.x;
    int wv = tid >> 6, d = tid & 63;
    int nsub = wv & 1, bh = wv >> 1;
    int n = chunk * 2 + nsub;
    const long KS = (long)NH * N_PER * Dh;   // 192000
    long col = (long)(h * N_PER + n) * Dh + d;
    const float* Wp = Wg1 + col;
    const float* hgp = hg + bh * 16 * 128;
    float acc[16];
#pragma unroll
    for (int b = 0; b < 16; ++b) acc[b] = 0.f;
    float4 wc;
    wc.x = Wp[0];
    wc.y = Wp[KS];
    wc.z = Wp[2 * KS];
    wc.w = Wp[3 * KS];
    for (int k = 0; k < 128; k += 4) {
        float4 wn = make_float4(0.f, 0.f, 0.f, 0.f);
        if (k + 4 < 128) {
            wn.x = Wp[(long)(k + 4) * KS];
            wn.y = Wp[(long)(k + 5) * KS];
            wn.z = Wp[(long)(k + 6) * KS];
            wn.w = Wp[(long)(k + 7) * KS];
        }
#pragma unroll
        for (int b = 0; b < 16; ++b) {
            float4 hv = *(const float4*)(hgp + b * 128 + k);   // wave-uniform
            acc[b] = fmaf(hv.x, wc.x, fmaf(hv.y, wc.y, fmaf(hv.z, wc.z, fmaf(hv.w, wc.w, acc[b]))));
        }
        wc = wn;
    }
    float bgv = bg1[col];
#pragma unroll
    for (int b = 0; b < 16; ++b)
        acc[b] = actions[(bh * 16 + b) * N_PER + n] * softplusf(acc[b] + bgv);
    // sum the 2 n's: nsub 0 writes, nsub 1 adds (disjoint b-rows per bh)
    if (nsub == 0) {
#pragma unroll
        for (int b = 0; b < 16; ++b) red[bh * 16 + b][d] = acc[b];
    }
    __syncthreads();
    if (nsub == 1) {
#pragma unroll
        for (int b = 0; b < 16; ++b) red[bh * 16 + b][d] += acc[b];
    }
    __syncthreads();
    float* po = p1 + (long)(chunk * NH + h) * 2048;
#pragma unroll
    for (int j = 0; j < 8; ++j) {
        int o = j * 256 + tid;
        po[o] = red[o >> 6][o & 63];
    }
}

// block = (b,h): 96 blocks; thread = (part, d); 4-way chunk split + LDS finish
__global__ __launch_bounds__(256) void k_red1(const float* __restrict__ p1,
                                              float* __restrict__ h1) {
    __shared__ float sh[4][64];
    int b = blockIdx.x / 3, h = blockIdx.x % 3;
    int part = threadIdx.x >> 6, d = threadIdx.x & 63;
    float s = 0.f;
    for (int ch = part; ch < W1CH; ch += 4)
        s += p1[(long)(ch * 3 + h) * 2048 + b * 64 + d];
    if (part) sh[part][d] = s;
    __syncthreads();
    if (part == 0)
        h1[(b * 3 + h) * 64 + d] = sqrtf(fmaxf(s + sh[1][d] + sh[2][d] + sh[3][d], 0.f) + EPSV);
}

// block = (h*64+d); writes p2[hd][b][e]
__global__ __launch_bounds__(256) void k_w2(const float* __restrict__ hg,
                                            const float* __restrict__ Wg2,
                                            const float* __restrict__ bg2,
                                            const float* __restrict__ h1,
                                            float* __restrict__ p2) {
    __shared__ float hgs[32][128];
    __shared__ float wt[128][64];
    __shared__ float h1s[32];
    int hd = blockIdx.x;  // h*64 + d
    int tid = threadIdx.x;
    for (int i = 0; i < 16; ++i) {
        int idx = tid + i * 256;
        hgs[idx >> 7][idx & 127] = hg[idx];
    }
    long base = (long)hd * 64;
    for (int i = 0; i < 32; ++i) {
        int idx = tid + i * 256;
        wt[idx >> 6][idx & 63] = Wg2[(long)(idx >> 6) * (NH * Dh * Dh) + base + (idx & 63)];
    }
    int h = hd >> 6, d = hd & 63;
    if (tid < 32) h1s[tid] = h1[tid * (NH * Dh) + h * Dh + d];
    __syncthreads();
    int e = tid & 63, bq = tid >> 6;
    float bgv = bg2[base + e];
    float dot[8];
#pragma unroll
    for (int bi = 0; bi < 8; ++bi) dot[bi] = 0.f;
    for (int k = 0; k < 128; ++k) {
        float w = wt[k][e];
#pragma unroll
        for (int bi = 0; bi < 8; ++bi)
            dot[bi] += hgs[bq * 8 + bi][k] * w;
    }
    float* po = p2 + (long)hd * (32 * 64);
#pragma unroll
    for (int bi = 0; bi < 8; ++bi) {
        int b = bq * 8 + bi;
        po[b * 64 + e] = softplusf(dot[bi] + bgv) * h1s[b];
    }
}

__global__ __launch_bounds__(256) void k_red2(const float* __restrict__ p2,
                                              float* __restrict__ h2) {
    int o = blockIdx.x * 256 + threadIdx.x;  // b*192 + h*64 + e
    if (o >= 32 * 192) return;
    int bh = o >> 6;
    int h = bh % 3, b = bh / 3;
    int e = o & 63;
    float s = 0.f;
    for (int d = 0; d < 64; ++d)
        s += p2[(h * 64 + d) * 2048 + b * 64 + e];
    h2[o] = log1pf(fmaxf(s, 0.f));   // SafeLog
}

__global__ __launch_bounds__(192) void k_out(const float* __restrict__ hg,
                                             const float* __restrict__ Wg3,
                                             const float* __restrict__ bg3,
                                             const float* __restrict__ h2,
                                             float* __restrict__ out) {
    __shared__ float hgb[128];
    __shared__ float hres[NH];
    int b = blockIdx.x, tid = threadIdx.x;
    if (tid < 128) hgb[tid] = hg[b * 128 + tid];
    __syncthreads();
    int h = tid / 64, e = tid & 63;
    int c = h * 64 + e;
    float dot = 0.f;
    for (int k = 0; k < 128; ++k)
        dot += hgb[k] * Wg3[k * (NH * Dh) + c];
    float v = softplusf(dot + bg3[c]) * h2[b * 192 + c];
    for (int off = 32; off; off >>= 1)
        v += __shfl_down(v, off, 64);
    if (e == 0) hres[h] = v;
    __syncthreads();
    if (tid == 0) out[b] = fminf(fminf(hres[0], hres[1]), hres[2]);
}

extern "C" void kernel_launch(void* const* d_in, const int* in_sizes, int n_in,
                              void* d_out, int out_size, void* d_ws, size_t ws_size,
                              hipStream_t stream) {
    const float* x   = (const float*)d_in[0];
    const int*   ei  = (const int*)d_in[1];
    const float* act = (const float*)d_in[3];
    const float* Wc1 = (const float*)d_in[4];
    const float* bc1 = (const float*)d_in[5];
    const float* Wc2 = (const float*)d_in[6];
    const float* bc2 = (const float*)d_in[7];
    const float* Wc3 = (const float*)d_in[8];
    const float* bc3 = (const float*)d_in[9];
    const float* Wg1 = (const float*)d_in[10];
    const float* bg1 = (const float*)d_in[11];
    const float* Wg2 = (const float*)d_in[12];
    const float* bg2 = (const float*)d_in[13];
    const float* Wg3 = (const float*)d_in[14];
    const float* bg3 = (const float*)d_in[15];
    float* out = (float*)d_out;

    float* ws   = (float*)d_ws;
    float* dinv = ws;                               // 32000
    float* bufA = dinv + TOTALN;                    // 4.096M
    float* bufB = bufA + (long)TOTALN * 128;        // 4.096M
    float* hg   = bufB + (long)TOTALN * 128;        // 4096
    float* h1   = hg + 32 * 128;                    // 6144
    float* h2   = h1 + 32 * 192;                    // 6144
    float* csr_w = h2 + 32 * 192;                   // 512000
    float* pp   = csr_w + NE;                       // 102400
    int* cnt    = (int*)(pp + NB * PCH * 128);      // 32000
    int* rowptr = cnt + TOTALN;                     // 32001
    int* cursor = rowptr + TOTALN + 1;              // 32000
    int* bsum   = cursor + TOTALN;                  // 128
    int* csr_src= bsum + 128;                       // 512000
    // aliases: bufB free after last gather; bufA free after pool1
    float* p1   = bufB;                             // 500*3*2048 = 3.072M <= 4.096M
    float* p2   = bufA;                             // 64*3*2048  = 393216 <= 4.096M

    // degree + norm + CSR build
    k_init_deg<<<(TOTALN + 255) / 256, 256, 0, stream>>>(dinv);
    k_deg<<<NE / 256, 256, 0, stream>>>(ei, dinv);
    k_prep<<<(TOTALN + 255) / 256, 256, 0, stream>>>(dinv, cnt);
    k_scan_block<<<125, 256, 0, stream>>>(cnt, rowptr, bsum);
    k_scan_tot<<<1, 64, 0, stream>>>(bsum);
    k_scan_add<<<125, 256, 0, stream>>>(rowptr, bsum, cursor);
    k_fill<<<NE / 256, 256, 0, stream>>>(ei, dinv, cursor, csr_src, csr_w);

    // layer 1
    k_mm128<<<500, 256, 0, stream>>>(x, Wc1, bufB);
    k_gather<0><<<TOTALN / 4, 256, 0, stream>>>(bufB, bufA, rowptr, csr_src, csr_w, dinv, bc1);
    // layer 2
    k_mm128<<<500, 256, 0, stream>>>(bufA, Wc2, bufB);
    k_gather<0><<<TOTALN / 4, 256, 0, stream>>>(bufB, bufA, rowptr, csr_src, csr_w, dinv, bc2);
    // layer 3 (no relu; bias folded into pool stage 2)
    k_mm128<<<500, 256, 0, stream>>>(bufA, Wc3, bufB);
    k_gather<1><<<TOTALN / 4, 256, 0, stream>>>(bufB, bufA, rowptr, csr_src, csr_w, dinv, nullptr);
    k_pool1<<<NB * PCH, 256, 0, stream>>>(bufA, pp);
    k_pool2<<<(NB * 128 + 255) / 256, 256, 0, stream>>>(pp, bc3, hg);

    // hypernetwork + compute_q
    k_w1<<<NH * W1CH, 256, 0, stream>>>(hg, Wg1, bg1, act, p1);
    k_red1<<<96, 256, 0, stream>>>(p1, h1);
    k_w2<<<NH * Dh, 256, 0, stream>>>(hg, Wg2, bg2, h1, p2);
    k_red2<<<24, 256, 0, stream>>>(p2, h2);
    k_out<<<NB, 192, 0, stream>>>(hg, Wg3, bg3, h2, out);
}

// Round 6
// 463.154 us; speedup vs baseline: 1.0209x; 1.0209x over previous
//
#include <hip/hip_runtime.h>
#include <hip/hip_bf16.h>
#include <math.h>

#define NB 32          // graphs
#define N_PER 1000
#define TOTALN 32000
#define NE 512000
#define HID 128
#define Dh 64
#define NH 3
#define EPSV 1e-6f
#define PCH 25         // pool chunks per graph (40 nodes each)
#define W1CH 250       // k_w1 chunks (4 n's each)

__device__ __forceinline__ float softplusf(float x) {
    return fmaxf(x, 0.0f) + log1pf(expf(-fabsf(x)));
}

__global__ __launch_bounds__(256) void k_init_deg(float* deg) {
    int i = blockIdx.x * 256 + threadIdx.x;
    if (i < TOTALN) deg[i] = 1.0f;   // self loop
}

__global__ __launch_bounds__(256) void k_deg(const int* __restrict__ ei, float* deg) {
    int e = blockIdx.x * 256 + threadIdx.x;
    if (e < NE) atomicAdd(&deg[ei[NE + e]], 1.0f);
}

// dinv = rsqrt(deg); cnt = (int)deg - 1 (edges only, self-loop excluded)
__global__ __launch_bounds__(256) void k_prep(float* __restrict__ d, int* __restrict__ cnt) {
    int i = blockIdx.x * 256 + threadIdx.x;
    if (i < TOTALN) {
        float v = d[i];
        cnt[i] = (int)v - 1;
        d[i] = rsqrtf(v);
    }
}

// exclusive scan of cnt[32000] -> rowptr; 125 blocks x 256
__global__ __launch_bounds__(256) void k_scan_block(const int* __restrict__ cnt,
                                                    int* __restrict__ rowptr,
                                                    int* __restrict__ bsum) {
    __shared__ int sh[256];
    int t = threadIdx.x;
    int i = blockIdx.x * 256 + t;
    int v = cnt[i];
    sh[t] = v;
    __syncthreads();
    for (int off = 1; off < 256; off <<= 1) {
        int add = (t >= off) ? sh[t - off] : 0;
        __syncthreads();
        sh[t] += add;
        __syncthreads();
    }
    rowptr[i] = sh[t] - v;   // exclusive within block
    if (t == 255) bsum[blockIdx.x] = sh[255];
}

__global__ void k_scan_tot(int* __restrict__ bsum) {
    if (threadIdx.x == 0) {
        int run = 0;
        for (int i = 0; i < 125; ++i) { int t = bsum[i]; bsum[i] = run; run += t; }
    }
}

__global__ __launch_bounds__(256) void k_scan_add(int* __restrict__ rowptr,
                                                  const int* __restrict__ bsum,
                                                  int* __restrict__ cursor) {
    int i = blockIdx.x * 256 + threadIdx.x;
    int v = rowptr[i] + bsum[blockIdx.x];
    rowptr[i] = v;
    cursor[i] = v;
    if (i == 0) rowptr[TOTALN] = NE;
}

__global__ __launch_bounds__(256) void k_fill(const int* __restrict__ ei,
                                              const float* __restrict__ dinv,
                                              int* __restrict__ cursor,
                                              int* __restrict__ csr_src,
                                              float* __restrict__ csr_w) {
    int e = blockIdx.x * 256 + threadIdx.x;
    if (e < NE) {
        int s = ei[e], d = ei[NE + e];
        int pos = atomicAdd(&cursor[d], 1);
        csr_src[pos] = s;
        csr_w[pos] = dinv[s] * dinv[d];
    }
}

// Y[rows x 128] = X[rows x 128] @ W[128 x 128]; 64 rows per block
__global__ __launch_bounds__(256) void k_mm128(const float* __restrict__ X,
                                               const float* __restrict__ W,
                                               float* __restrict__ Y) {
    __shared__ float xs[64][128];
    __shared__ float ws[32][128];
    int tid = threadIdx.x;
    int row0 = blockIdx.x * 64;
    int c = tid & 127, rp = tid >> 7;
    for (int i = 0; i < 32; ++i) {
        int idx = tid + i * 256;
        xs[idx >> 7][idx & 127] = X[(row0 + (idx >> 7)) * 128 + (idx & 127)];
    }
    float acc[32];
#pragma unroll
    for (int i = 0; i < 32; ++i) acc[i] = 0.f;
    for (int kc = 0; kc < 4; ++kc) {
        __syncthreads();
        for (int i = 0; i < 16; ++i) {
            int idx = tid + i * 256;
            ws[idx >> 7][idx & 127] = W[(kc * 32 + (idx >> 7)) * 128 + (idx & 127)];
        }
        __syncthreads();
#pragma unroll 4
        for (int k = 0; k < 32; ++k) {
            float w = ws[k][c];
#pragma unroll
            for (int i = 0; i < 32; ++i)
                acc[i] += xs[rp * 32 + i][kc * 32 + k] * w;
        }
    }
#pragma unroll
    for (int i = 0; i < 32; ++i)
        Y[(row0 + rp * 32 + i) * 128 + c] = acc[i];
}

// CSR gather: 1 wave per node, float2 per lane, 4-deep edge ILP.
// MODE 0: +bias,relu ; MODE 1: plain
template<int MODE>
__global__ __launch_bounds__(256) void k_gather(const float* __restrict__ feat,
                                                float* __restrict__ out,
                                                const int* __restrict__ rowptr,
                                                const int* __restrict__ csr_src,
                                                const float* __restrict__ csr_w,
                                                const float* __restrict__ dinv,
                                                const float* __restrict__ bias) {
    int wid = threadIdx.x >> 6, lane = threadIdx.x & 63;
    int v = blockIdx.x * 4 + wid;
    const float2* f2 = (const float2*)feat;
    float dv = dinv[v];
    float2 self = f2[v * 64 + lane];
    float acc0 = self.x * dv * dv, acc1 = self.y * dv * dv;
    int e = rowptr[v], e1 = rowptr[v + 1];
    for (; e + 4 <= e1; e += 4) {
        int s0 = csr_src[e], s1 = csr_src[e + 1], s2 = csr_src[e + 2], s3 = csr_src[e + 3];
        float w0 = csr_w[e], w1 = csr_w[e + 1], w2 = csr_w[e + 2], w3 = csr_w[e + 3];
        float2 f0 = f2[s0 * 64 + lane];
        float2 f1 = f2[s1 * 64 + lane];
        float2 fa = f2[s2 * 64 + lane];
        float2 fb = f2[s3 * 64 + lane];
        acc0 += f0.x * w0 + f1.x * w1 + fa.x * w2 + fb.x * w3;
        acc1 += f0.y * w0 + f1.y * w1 + fa.y * w2 + fb.y * w3;
    }
    for (; e < e1; ++e) {
        int s = csr_src[e];
        float w = csr_w[e];
        float2 f = f2[s * 64 + lane];
        acc0 += f.x * w;
        acc1 += f.y * w;
    }
    if (MODE == 0) {
        int c = lane * 2;
        acc0 = fmaxf(acc0 + bias[c], 0.f);
        acc1 = fmaxf(acc1 + bias[c + 1], 0.f);
    }
    ((float2*)out)[v * 64 + lane] = make_float2(acc0, acc1);
}

// pool stage 1: block = (graph b, chunk of 40 nodes) -> partial sums
__global__ __launch_bounds__(256) void k_pool1(const float* __restrict__ A,
                                               float* __restrict__ pp) {
    __shared__ float sh[256];
    int b = blockIdx.x / PCH, ch = blockIdx.x % PCH;
    int c = threadIdx.x & 127, half = threadIdx.x >> 7;
    float acc = 0.f;
    int n0 = ch * 40;
#pragma unroll 4
    for (int j = half; j < 40; j += 2)
        acc += A[(b * N_PER + n0 + j) * 128 + c];
    sh[threadIdx.x] = acc;
    __syncthreads();
    if (threadIdx.x < 128)
        pp[blockIdx.x * 128 + c] = sh[c] + sh[128 + c];
}

// pool stage 2: reduce 25 partials, apply mean + layer-3 bias
__global__ __launch_bounds__(256) void k_pool2(const float* __restrict__ pp,
                                               const float* __restrict__ bias,
                                               float* __restrict__ hg) {
    int i = blockIdx.x * 256 + threadIdx.x;   // b*128 + c
    if (i >= NB * 128) return;
    int b = i >> 7, c = i & 127;
    float s = 0.f;
#pragma unroll
    for (int ch = 0; ch < PCH; ++ch)
        s += pp[(b * PCH + ch) * 128 + c];
    hg[i] = s * (1.0f / N_PER) + bias[c];
}

// k_w1: block = (head h, chunk of 4 n's); 512 threads = 8 waves = (nsub 0..3, khalf 0..1).
// Each wave: 64-k partial dot for all 32 graphs of one n (lane = d).
// khalf partitions the Wg1/hg reads exactly (no duplicate loads).
// LDS combines k-halves PRE-softplus (dots are additive), then softplus*action,
// then 8-wave parallel reduction over the 4 n's -> p1[chunk][h][b][d].
__global__ __launch_bounds__(512) void k_w1(const float* __restrict__ hg,
                                            const float* __restrict__ Wg1,
                                            const float* __restrict__ bg1,
                                            const float* __restrict__ actions,
                                            float* __restrict__ p1) {
    __shared__ float red[4][32][64];   // [nsub][b][d]
    int h = blockIdx.x / W1CH, chunk = blockIdx.x % W1CH;
    int tid = threadIdx.x;
    int wv = tid >> 6, d = tid & 63;
    int khalf = wv & 1, nsub = wv >> 1;
    int n = chunk * 4 + nsub;
    const long KS = (long)NH * N_PER * Dh;   // 192000
    long col = (long)(h * N_PER + n) * Dh + d;
    const float* Wp = Wg1 + col;
    int k0 = khalf * 64;
    float acc[32];
#pragma unroll
    for (int b = 0; b < 32; ++b) acc[b] = 0.f;
    float4 wc;
    wc.x = Wp[(long)(k0 + 0) * KS];
    wc.y = Wp[(long)(k0 + 1) * KS];
    wc.z = Wp[(long)(k0 + 2) * KS];
    wc.w = Wp[(long)(k0 + 3) * KS];
    for (int k = k0; k < k0 + 64; k += 4) {
        float4 wn = make_float4(0.f, 0.f, 0.f, 0.f);
        if (k + 4 < k0 + 64) {
            wn.x = Wp[(long)(k + 4) * KS];
            wn.y = Wp[(long)(k + 5) * KS];
            wn.z = Wp[(long)(k + 6) * KS];
            wn.w = Wp[(long)(k + 7) * KS];
        }
#pragma unroll
        for (int b = 0; b < 32; ++b) {
            float4 hv = *(const float4*)(hg + b * 128 + k);   // wave-uniform
            acc[b] = fmaf(hv.x, wc.x, fmaf(hv.y, wc.y, fmaf(hv.z, wc.z, fmaf(hv.w, wc.w, acc[b]))));
        }
        wc = wn;
    }
    // combine k-halves (pre-softplus)
    if (khalf == 0) {
#pragma unroll
        for (int b = 0; b < 32; ++b) red[nsub][b][d] = acc[b];
    }
    __syncthreads();
    if (khalf == 1) {
#pragma unroll
        for (int b = 0; b < 32; ++b) red[nsub][b][d] += acc[b];
    }
    __syncthreads();
    // softplus + action (one wave per n)
    if (khalf == 0) {
        float bgv = bg1[col];
#pragma unroll
        for (int b = 0; b < 32; ++b)
            red[nsub][b][d] = actions[b * N_PER + n] * softplusf(red[nsub][b][d] + bgv);
    }
    __syncthreads();
    // parallel n-reduction: 512 threads x 4 outputs each
    const float* rf = &red[0][0][0];
    float* po = p1 + (long)(chunk * NH + h) * 2048;
#pragma unroll
    for (int j = 0; j < 4; ++j) {
        int o = j * 512 + tid;
        po[o] = rf[o] + rf[2048 + o] + rf[4096 + o] + rf[6144 + o];
    }
}

// block = (b,h): 96 blocks; thread = (part, d); 4-way chunk split + LDS finish
__global__ __launch_bounds__(256) void k_red1(const float* __restrict__ p1,
                                              float* __restrict__ h1) {
    __shared__ float sh[4][64];
    int b = blockIdx.x / 3, h = blockIdx.x % 3;
    int part = threadIdx.x >> 6, d = threadIdx.x & 63;
    float s = 0.f;
    for (int ch = part; ch < W1CH; ch += 4)
        s += p1[(long)(ch * 3 + h) * 2048 + b * 64 + d];
    if (part) sh[part][d] = s;
    __syncthreads();
    if (part == 0)
        h1[(b * 3 + h) * 64 + d] = sqrtf(fmaxf(s + sh[1][d] + sh[2][d] + sh[3][d], 0.f) + EPSV);
}

// block = (h*64+d); writes p2[hd][b][e]
__global__ __launch_bounds__(256) void k_w2(const float* __restrict__ hg,
                                            const float* __restrict__ Wg2,
                                            const float* __restrict__ bg2,
                                            const float* __restrict__ h1,
                                            float* __restrict__ p2) {
    __shared__ float hgs[32][128];
    __shared__ float wt[128][64];
    __shared__ float h1s[32];
    int hd = blockIdx.x;  // h*64 + d
    int tid = threadIdx.x;
    for (int i = 0; i < 16; ++i) {
        int idx = tid + i * 256;
        hgs[idx >> 7][idx & 127] = hg[idx];
    }
    long base = (long)hd * 64;
    for (int i = 0; i < 32; ++i) {
        int idx = tid + i * 256;
        wt[idx >> 6][idx & 63] = Wg2[(long)(idx >> 6) * (NH * Dh * Dh) + base + (idx & 63)];
    }
    int h = hd >> 6, d = hd & 63;
    if (tid < 32) h1s[tid] = h1[tid * (NH * Dh) + h * Dh + d];
    __syncthreads();
    int e = tid & 63, bq = tid >> 6;
    float bgv = bg2[base + e];
    float dot[8];
#pragma unroll
    for (int bi = 0; bi < 8; ++bi) dot[bi] = 0.f;
    for (int k = 0; k < 128; ++k) {
        float w = wt[k][e];
#pragma unroll
        for (int bi = 0; bi < 8; ++bi)
            dot[bi] += hgs[bq * 8 + bi][k] * w;
    }
    float* po = p2 + (long)hd * (32 * 64);
#pragma unroll
    for (int bi = 0; bi < 8; ++bi) {
        int b = bq * 8 + bi;
        po[b * 64 + e] = softplusf(dot[bi] + bgv) * h1s[b];
    }
}

__global__ __launch_bounds__(256) void k_red2(const float* __restrict__ p2,
                                              float* __restrict__ h2) {
    int o = blockIdx.x * 256 + threadIdx.x;  // b*192 + h*64 + e
    if (o >= 32 * 192) return;
    int bh = o >> 6;
    int h = bh % 3, b = bh / 3;
    int e = o & 63;
    float s = 0.f;
    for (int d = 0; d < 64; ++d)
        s += p2[(h * 64 + d) * 2048 + b * 64 + e];
    h2[o] = log1pf(fmaxf(s, 0.f));   // SafeLog
}

__global__ __launch_bounds__(192) void k_out(const float* __restrict__ hg,
                                             const float* __restrict__ Wg3,
                                             const float* __restrict__ bg3,
                                             const float* __restrict__ h2,
                                             float* __restrict__ out) {
    __shared__ float hgb[128];
    __shared__ float hres[NH];
    int b = blockIdx.x, tid = threadIdx.x;
    if (tid < 128) hgb[tid] = hg[b * 128 + tid];
    __syncthreads();
    int h = tid / 64, e = tid & 63;
    int c = h * 64 + e;
    float dot = 0.f;
    for (int k = 0; k < 128; ++k)
        dot += hgb[k] * Wg3[k * (NH * Dh) + c];
    float v = softplusf(dot + bg3[c]) * h2[b * 192 + c];
    for (int off = 32; off; off >>= 1)
        v += __shfl_down(v, off, 64);
    if (e == 0) hres[h] = v;
    __syncthreads();
    if (tid == 0) out[b] = fminf(fminf(hres[0], hres[1]), hres[2]);
}

extern "C" void kernel_launch(void* const* d_in, const int* in_sizes, int n_in,
                              void* d_out, int out_size, void* d_ws, size_t ws_size,
                              hipStream_t stream) {
    const float* x   = (const float*)d_in[0];
    const int*   ei  = (const int*)d_in[1];
    const float* act = (const float*)d_in[3];
    const float* Wc1 = (const float*)d_in[4];
    const float* bc1 = (const float*)d_in[5];
    const float* Wc2 = (const float*)d_in[6];
    const float* bc2 = (const float*)d_in[7];
    const float* Wc3 = (const float*)d_in[8];
    const float* bc3 = (const float*)d_in[9];
    const float* Wg1 = (const float*)d_in[10];
    const float* bg1 = (const float*)d_in[11];
    const float* Wg2 = (const float*)d_in[12];
    const float* bg2 = (const float*)d_in[13];
    const float* Wg3 = (const float*)d_in[14];
    const float* bg3 = (const float*)d_in[15];
    float* out = (float*)d_out;

    float* ws   = (float*)d_ws;
    float* dinv = ws;                               // 32000
    float* bufA = dinv + TOTALN;                    // 4.096M
    float* bufB = bufA + (long)TOTALN * 128;        // 4.096M
    float* hg   = bufB + (long)TOTALN * 128;        // 4096
    float* h1   = hg + 32 * 128;                    // 6144
    float* h2   = h1 + 32 * 192;                    // 6144
    float* csr_w = h2 + 32 * 192;                   // 512000
    float* pp   = csr_w + NE;                       // 102400
    int* cnt    = (int*)(pp + NB * PCH * 128);      // 32000
    int* rowptr = cnt + TOTALN;                     // 32001
    int* cursor = rowptr + TOTALN + 1;              // 32000
    int* bsum   = cursor + TOTALN;                  // 128
    int* csr_src= bsum + 128;                       // 512000
    // aliases: bufB free after last gather; bufA free after pool1
    float* p1   = bufB;                             // 250*3*2048 = 1.536M <= 4.096M
    float* p2   = bufA;                             // 64*3*2048  = 393216 <= 4.096M

    // degree + norm + CSR build
    k_init_deg<<<(TOTALN + 255) / 256, 256, 0, stream>>>(dinv);
    k_deg<<<NE / 256, 256, 0, stream>>>(ei, dinv);
    k_prep<<<(TOTALN + 255) / 256, 256, 0, stream>>>(dinv, cnt);
    k_scan_block<<<125, 256, 0, stream>>>(cnt, rowptr, bsum);
    k_scan_tot<<<1, 64, 0, stream>>>(bsum);
    k_scan_add<<<125, 256, 0, stream>>>(rowptr, bsum, cursor);
    k_fill<<<NE / 256, 256, 0, stream>>>(ei, dinv, cursor, csr_src, csr_w);

    // layer 1
    k_mm128<<<500, 256, 0, stream>>>(x, Wc1, bufB);
    k_gather<0><<<TOTALN / 4, 256, 0, stream>>>(bufB, bufA, rowptr, csr_src, csr_w, dinv, bc1);
    // layer 2
    k_mm128<<<500, 256, 0, stream>>>(bufA, Wc2, bufB);
    k_gather<0><<<TOTALN / 4, 256, 0, stream>>>(bufB, bufA, rowptr, csr_src, csr_w, dinv, bc2);
    // layer 3 (no relu; bias folded into pool stage 2)
    k_mm128<<<500, 256, 0, stream>>>(bufA, Wc3, bufB);
    k_gather<1><<<TOTALN / 4, 256, 0, stream>>>(bufB, bufA, rowptr, csr_src, csr_w, dinv, nullptr);
    k_pool1<<<NB * PCH, 256, 0, stream>>>(bufA, pp);
    k_pool2<<<(NB * 128 + 255) / 256, 256, 0, stream>>>(pp, bc3, hg);

    // hypernetwork + compute_q
    k_w1<<<NH * W1CH, 512, 0, stream>>>(hg, Wg1, bg1, act, p1);
    k_red1<<<96, 256, 0, stream>>>(p1, h1);
    k_w2<<<NH * Dh, 256, 0, stream>>>(hg, Wg2, bg2, h1, p2);
    k_red2<<<24, 256, 0, stream>>>(p2, h2);
    k_out<<<NB, 192, 0, stream>>>(hg, Wg3, bg3, h2, out);
}

// Round 7
// 401.290 us; speedup vs baseline: 1.1783x; 1.1542x over previous
//
#include <hip/hip_runtime.h>
#include <hip/hip_bf16.h>
#include <math.h>

#define NB 32          // graphs
#define N_PER 1000
#define TOTALN 32000
#define NE 512000
#define HID 128
#define Dh 64
#define NH 3
#define EPSV 1e-6f
#define PCH 25         // pool chunks per graph (40 nodes each)
#define W1CH 250       // k_w1 chunks (4 n's each)

__device__ __forceinline__ float softplusf(float x) {
    return fmaxf(x, 0.0f) + log1pf(expf(-fabsf(x)));
}

__global__ __launch_bounds__(256) void k_init_deg(float* deg) {
    int i = blockIdx.x * 256 + threadIdx.x;
    if (i < TOTALN) deg[i] = 1.0f;   // self loop
}

__global__ __launch_bounds__(256) void k_deg(const int* __restrict__ ei, float* deg) {
    int e = blockIdx.x * 256 + threadIdx.x;
    if (e < NE) atomicAdd(&deg[ei[NE + e]], 1.0f);
}

// dinv = rsqrt(deg); cnt = (int)deg - 1 (edges only, self-loop excluded)
__global__ __launch_bounds__(256) void k_prep(float* __restrict__ d, int* __restrict__ cnt) {
    int i = blockIdx.x * 256 + threadIdx.x;
    if (i < TOTALN) {
        float v = d[i];
        cnt[i] = (int)v - 1;
        d[i] = rsqrtf(v);
    }
}

// exclusive scan of cnt[32000] -> rowptr; 125 blocks x 256
__global__ __launch_bounds__(256) void k_scan_block(const int* __restrict__ cnt,
                                                    int* __restrict__ rowptr,
                                                    int* __restrict__ bsum) {
    __shared__ int sh[256];
    int t = threadIdx.x;
    int i = blockIdx.x * 256 + t;
    int v = cnt[i];
    sh[t] = v;
    __syncthreads();
    for (int off = 1; off < 256; off <<= 1) {
        int add = (t >= off) ? sh[t - off] : 0;
        __syncthreads();
        sh[t] += add;
        __syncthreads();
    }
    rowptr[i] = sh[t] - v;   // exclusive within block
    if (t == 255) bsum[blockIdx.x] = sh[255];
}

__global__ void k_scan_tot(int* __restrict__ bsum) {
    if (threadIdx.x == 0) {
        int run = 0;
        for (int i = 0; i < 125; ++i) { int t = bsum[i]; bsum[i] = run; run += t; }
    }
}

__global__ __launch_bounds__(256) void k_scan_add(int* __restrict__ rowptr,
                                                  const int* __restrict__ bsum,
                                                  int* __restrict__ cursor) {
    int i = blockIdx.x * 256 + threadIdx.x;
    int v = rowptr[i] + bsum[blockIdx.x];
    rowptr[i] = v;
    cursor[i] = v;
    if (i == 0) rowptr[TOTALN] = NE;
}

__global__ __launch_bounds__(256) void k_fill(const int* __restrict__ ei,
                                              const float* __restrict__ dinv,
                                              int* __restrict__ cursor,
                                              int* __restrict__ csr_src,
                                              float* __restrict__ csr_w) {
    int e = blockIdx.x * 256 + threadIdx.x;
    if (e < NE) {
        int s = ei[e], d = ei[NE + e];
        int pos = atomicAdd(&cursor[d], 1);
        csr_src[pos] = s;
        csr_w[pos] = dinv[s] * dinv[d];
    }
}

// Y[rows x 128] = X[rows x 128] @ W[128 x 128]; 64 rows per block
__global__ __launch_bounds__(256) void k_mm128(const float* __restrict__ X,
                                               const float* __restrict__ W,
                                               float* __restrict__ Y) {
    __shared__ float xs[64][128];
    __shared__ float ws[32][128];
    int tid = threadIdx.x;
    int row0 = blockIdx.x * 64;
    int c = tid & 127, rp = tid >> 7;
    for (int i = 0; i < 32; ++i) {
        int idx = tid + i * 256;
        xs[idx >> 7][idx & 127] = X[(row0 + (idx >> 7)) * 128 + (idx & 127)];
    }
    float acc[32];
#pragma unroll
    for (int i = 0; i < 32; ++i) acc[i] = 0.f;
    for (int kc = 0; kc < 4; ++kc) {
        __syncthreads();
        for (int i = 0; i < 16; ++i) {
            int idx = tid + i * 256;
            ws[idx >> 7][idx & 127] = W[(kc * 32 + (idx >> 7)) * 128 + (idx & 127)];
        }
        __syncthreads();
#pragma unroll 4
        for (int k = 0; k < 32; ++k) {
            float w = ws[k][c];
#pragma unroll
            for (int i = 0; i < 32; ++i)
                acc[i] += xs[rp * 32 + i][kc * 32 + k] * w;
        }
    }
#pragma unroll
    for (int i = 0; i < 32; ++i)
        Y[(row0 + rp * 32 + i) * 128 + c] = acc[i];
}

// CSR gather: 1 wave per node, float2 per lane, 4-deep edge ILP.
// MODE 0: +bias,relu ; MODE 1: plain
template<int MODE>
__global__ __launch_bounds__(256) void k_gather(const float* __restrict__ feat,
                                                float* __restrict__ out,
                                                const int* __restrict__ rowptr,
                                                const int* __restrict__ csr_src,
                                                const float* __restrict__ csr_w,
                                                const float* __restrict__ dinv,
                                                const float* __restrict__ bias) {
    int wid = threadIdx.x >> 6, lane = threadIdx.x & 63;
    int v = blockIdx.x * 4 + wid;
    const float2* f2 = (const float2*)feat;
    float dv = dinv[v];
    float2 self = f2[v * 64 + lane];
    float acc0 = self.x * dv * dv, acc1 = self.y * dv * dv;
    int e = rowptr[v], e1 = rowptr[v + 1];
    for (; e + 4 <= e1; e += 4) {
        int s0 = csr_src[e], s1 = csr_src[e + 1], s2 = csr_src[e + 2], s3 = csr_src[e + 3];
        float w0 = csr_w[e], w1 = csr_w[e + 1], w2 = csr_w[e + 2], w3 = csr_w[e + 3];
        float2 f0 = f2[s0 * 64 + lane];
        float2 f1 = f2[s1 * 64 + lane];
        float2 fa = f2[s2 * 64 + lane];
        float2 fb = f2[s3 * 64 + lane];
        acc0 += f0.x * w0 + f1.x * w1 + fa.x * w2 + fb.x * w3;
        acc1 += f0.y * w0 + f1.y * w1 + fa.y * w2 + fb.y * w3;
    }
    for (; e < e1; ++e) {
        int s = csr_src[e];
        float w = csr_w[e];
        float2 f = f2[s * 64 + lane];
        acc0 += f.x * w;
        acc1 += f.y * w;
    }
    if (MODE == 0) {
        int c = lane * 2;
        acc0 = fmaxf(acc0 + bias[c], 0.f);
        acc1 = fmaxf(acc1 + bias[c + 1], 0.f);
    }
    ((float2*)out)[v * 64 + lane] = make_float2(acc0, acc1);
}

// pool stage 1: block = (graph b, chunk of 40 nodes) -> partial sums
__global__ __launch_bounds__(256) void k_pool1(const float* __restrict__ A,
                                               float* __restrict__ pp) {
    __shared__ float sh[256];
    int b = blockIdx.x / PCH, ch = blockIdx.x % PCH;
    int c = threadIdx.x & 127, half = threadIdx.x >> 7;
    float acc = 0.f;
    int n0 = ch * 40;
#pragma unroll 4
    for (int j = half; j < 40; j += 2)
        acc += A[(b * N_PER + n0 + j) * 128 + c];
    sh[threadIdx.x] = acc;
    __syncthreads();
    if (threadIdx.x < 128)
        pp[blockIdx.x * 128 + c] = sh[c] + sh[128 + c];
}

// pool stage 2: reduce 25 partials, apply mean + layer-3 bias
__global__ __launch_bounds__(256) void k_pool2(const float* __restrict__ pp,
                                               const float* __restrict__ bias,
                                               float* __restrict__ hg) {
    int i = blockIdx.x * 256 + threadIdx.x;   // b*128 + c
    if (i >= NB * 128) return;
    int b = i >> 7, c = i & 127;
    float s = 0.f;
#pragma unroll
    for (int ch = 0; ch < PCH; ++ch)
        s += pp[(b * PCH + ch) * 128 + c];
    hg[i] = s * (1.0f / N_PER) + bias[c];
}

// k_w1: block = (head h, chunk of 4 n's); 512 threads = 8 waves = (nsub 0..3, khalf 0..1).
// Each wave: 64-k partial dot for all 32 graphs of one n (lane = d).
// khalf partitions the Wg1/hg reads exactly (no duplicate loads).
// CRITICAL: k0 goes through readfirstlane so hg+b*128+k stays provably
// wave-uniform -> scalar s_load (SGPR broadcast, dual-issues with FMA).
// R5/R6 lost this (SGPR 112 -> 32) and VMEM broadcast loads stalled FMAs.
__global__ __launch_bounds__(512) void k_w1(const float* __restrict__ hg,
                                            const float* __restrict__ Wg1,
                                            const float* __restrict__ bg1,
                                            const float* __restrict__ actions,
                                            float* __restrict__ p1) {
    __shared__ float red[4][32][64];   // [nsub][b][d]
    int h = blockIdx.x / W1CH, chunk = blockIdx.x % W1CH;
    int tid = threadIdx.x;
    int wv = tid >> 6, d = tid & 63;
    int khalf = wv & 1, nsub = wv >> 1;
    int n = chunk * 4 + nsub;
    const long KS = (long)NH * N_PER * Dh;   // 192000
    long col = (long)(h * N_PER + n) * Dh + d;
    const float* Wp = Wg1 + col;
    int k0 = __builtin_amdgcn_readfirstlane(khalf * 64);   // force SGPR-uniform
    float acc[32];
#pragma unroll
    for (int b = 0; b < 32; ++b) acc[b] = 0.f;
    float4 wc;
    wc.x = Wp[(long)(k0 + 0) * KS];
    wc.y = Wp[(long)(k0 + 1) * KS];
    wc.z = Wp[(long)(k0 + 2) * KS];
    wc.w = Wp[(long)(k0 + 3) * KS];
    for (int kk = 0; kk < 64; kk += 4) {
        int k = k0 + kk;
        float4 wn = make_float4(0.f, 0.f, 0.f, 0.f);
        if (kk + 4 < 64) {
            wn.x = Wp[(long)(k + 4) * KS];
            wn.y = Wp[(long)(k + 5) * KS];
            wn.z = Wp[(long)(k + 6) * KS];
            wn.w = Wp[(long)(k + 7) * KS];
        }
#pragma unroll
        for (int b = 0; b < 32; ++b) {
            float4 hv = *(const float4*)(hg + b * 128 + k);   // uniform -> s_load
            acc[b] = fmaf(hv.x, wc.x, fmaf(hv.y, wc.y, fmaf(hv.z, wc.z, fmaf(hv.w, wc.w, acc[b]))));
        }
        wc = wn;
    }
    // combine k-halves (pre-softplus)
    if (khalf == 0) {
#pragma unroll
        for (int b = 0; b < 32; ++b) red[nsub][b][d] = acc[b];
    }
    __syncthreads();
    if (khalf == 1) {
#pragma unroll
        for (int b = 0; b < 32; ++b) red[nsub][b][d] += acc[b];
    }
    __syncthreads();
    // softplus + action (one wave per n)
    if (khalf == 0) {
        float bgv = bg1[col];
#pragma unroll
        for (int b = 0; b < 32; ++b)
            red[nsub][b][d] = actions[b * N_PER + n] * softplusf(red[nsub][b][d] + bgv);
    }
    __syncthreads();
    // parallel n-reduction: 512 threads x 4 outputs each
    const float* rf = &red[0][0][0];
    float* po = p1 + (long)(chunk * NH + h) * 2048;
#pragma unroll
    for (int j = 0; j < 4; ++j) {
        int o = j * 512 + tid;
        po[o] = rf[o] + rf[2048 + o] + rf[4096 + o] + rf[6144 + o];
    }
}

// block = (b,h): 96 blocks; thread = (part, d); 4-way chunk split + LDS finish
__global__ __launch_bounds__(256) void k_red1(const float* __restrict__ p1,
                                              float* __restrict__ h1) {
    __shared__ float sh[4][64];
    int b = blockIdx.x / 3, h = blockIdx.x % 3;
    int part = threadIdx.x >> 6, d = threadIdx.x & 63;
    float s = 0.f;
    for (int ch = part; ch < W1CH; ch += 4)
        s += p1[(long)(ch * 3 + h) * 2048 + b * 64 + d];
    if (part) sh[part][d] = s;
    __syncthreads();
    if (part == 0)
        h1[(b * 3 + h) * 64 + d] = sqrtf(fmaxf(s + sh[1][d] + sh[2][d] + sh[3][d], 0.f) + EPSV);
}

// block = (h*64+d); writes p2[hd][b][e]
__global__ __launch_bounds__(256) void k_w2(const float* __restrict__ hg,
                                            const float* __restrict__ Wg2,
                                            const float* __restrict__ bg2,
                                            const float* __restrict__ h1,
                                            float* __restrict__ p2) {
    __shared__ float hgs[32][128];
    __shared__ float wt[128][64];
    __shared__ float h1s[32];
    int hd = blockIdx.x;  // h*64 + d
    int tid = threadIdx.x;
    for (int i = 0; i < 16; ++i) {
        int idx = tid + i * 256;
        hgs[idx >> 7][idx & 127] = hg[idx];
    }
    long base = (long)hd * 64;
    for (int i = 0; i < 32; ++i) {
        int idx = tid + i * 256;
        wt[idx >> 6][idx & 63] = Wg2[(long)(idx >> 6) * (NH * Dh * Dh) + base + (idx & 63)];
    }
    int h = hd >> 6, d = hd & 63;
    if (tid < 32) h1s[tid] = h1[tid * (NH * Dh) + h * Dh + d];
    __syncthreads();
    int e = tid & 63, bq = tid >> 6;
    float bgv = bg2[base + e];
    float dot[8];
#pragma unroll
    for (int bi = 0; bi < 8; ++bi) dot[bi] = 0.f;
    for (int k = 0; k < 128; ++k) {
        float w = wt[k][e];
#pragma unroll
        for (int bi = 0; bi < 8; ++bi)
            dot[bi] += hgs[bq * 8 + bi][k] * w;
    }
    float* po = p2 + (long)hd * (32 * 64);
#pragma unroll
    for (int bi = 0; bi < 8; ++bi) {
        int b = bq * 8 + bi;
        po[b * 64 + e] = softplusf(dot[bi] + bgv) * h1s[b];
    }
}

__global__ __launch_bounds__(256) void k_red2(const float* __restrict__ p2,
                                              float* __restrict__ h2) {
    int o = blockIdx.x * 256 + threadIdx.x;  // b*192 + h*64 + e
    if (o >= 32 * 192) return;
    int bh = o >> 6;
    int h = bh % 3, b = bh / 3;
    int e = o & 63;
    float s = 0.f;
    for (int d = 0; d < 64; ++d)
        s += p2[(h * 64 + d) * 2048 + b * 64 + e];
    h2[o] = log1pf(fmaxf(s, 0.f));   // SafeLog
}

__global__ __launch_bounds__(192) void k_out(const float* __restrict__ hg,
                                             const float* __restrict__ Wg3,
                                             const float* __restrict__ bg3,
                                             const float* __restrict__ h2,
                                             float* __restrict__ out) {
    __shared__ float hgb[128];
    __shared__ float hres[NH];
    int b = blockIdx.x, tid = threadIdx.x;
    if (tid < 128) hgb[tid] = hg[b * 128 + tid];
    __syncthreads();
    int h = tid / 64, e = tid & 63;
    int c = h * 64 + e;
    float dot = 0.f;
    for (int k = 0; k < 128; ++k)
        dot += hgb[k] * Wg3[k * (NH * Dh) + c];
    float v = softplusf(dot + bg3[c]) * h2[b * 192 + c];
    for (int off = 32; off; off >>= 1)
        v += __shfl_down(v, off, 64);
    if (e == 0) hres[h] = v;
    __syncthreads();
    if (tid == 0) out[b] = fminf(fminf(hres[0], hres[1]), hres[2]);
}

extern "C" void kernel_launch(void* const* d_in, const int* in_sizes, int n_in,
                              void* d_out, int out_size, void* d_ws, size_t ws_size,
                              hipStream_t stream) {
    const float* x   = (const float*)d_in[0];
    const int*   ei  = (const int*)d_in[1];
    const float* act = (const float*)d_in[3];
    const float* Wc1 = (const float*)d_in[4];
    const float* bc1 = (const float*)d_in[5];
    const float* Wc2 = (const float*)d_in[6];
    const float* bc2 = (const float*)d_in[7];
    const float* Wc3 = (const float*)d_in[8];
    const float* bc3 = (const float*)d_in[9];
    const float* Wg1 = (const float*)d_in[10];
    const float* bg1 = (const float*)d_in[11];
    const float* Wg2 = (const float*)d_in[12];
    const float* bg2 = (const float*)d_in[13];
    const float* Wg3 = (const float*)d_in[14];
    const float* bg3 = (const float*)d_in[15];
    float* out = (float*)d_out;

    float* ws   = (float*)d_ws;
    float* dinv = ws;                               // 32000
    float* bufA = dinv + TOTALN;                    // 4.096M
    float* bufB = bufA + (long)TOTALN * 128;        // 4.096M
    float* hg   = bufB + (long)TOTALN * 128;        // 4096
    float* h1   = hg + 32 * 128;                    // 6144
    float* h2   = h1 + 32 * 192;                    // 6144
    float* csr_w = h2 + 32 * 192;                   // 512000
    float* pp   = csr_w + NE;                       // 102400
    int* cnt    = (int*)(pp + NB * PCH * 128);      // 32000
    int* rowptr = cnt + TOTALN;                     // 32001
    int* cursor = rowptr + TOTALN + 1;              // 32000
    int* bsum   = cursor + TOTALN;                  // 128
    int* csr_src= bsum + 128;                       // 512000
    // aliases: bufB free after last gather; bufA free after pool1
    float* p1   = bufB;                             // 250*3*2048 = 1.536M <= 4.096M
    float* p2   = bufA;                             // 64*3*2048  = 393216 <= 4.096M

    // degree + norm + CSR build
    k_init_deg<<<(TOTALN + 255) / 256, 256, 0, stream>>>(dinv);
    k_deg<<<NE / 256, 256, 0, stream>>>(ei, dinv);
    k_prep<<<(TOTALN + 255) / 256, 256, 0, stream>>>(dinv, cnt);
    k_scan_block<<<125, 256, 0, stream>>>(cnt, rowptr, bsum);
    k_scan_tot<<<1, 64, 0, stream>>>(bsum);
    k_scan_add<<<125, 256, 0, stream>>>(rowptr, bsum, cursor);
    k_fill<<<NE / 256, 256, 0, stream>>>(ei, dinv, cursor, csr_src, csr_w);

    // layer 1
    k_mm128<<<500, 256, 0, stream>>>(x, Wc1, bufB);
    k_gather<0><<<TOTALN / 4, 256, 0, stream>>>(bufB, bufA, rowptr, csr_src, csr_w, dinv, bc1);
    // layer 2
    k_mm128<<<500, 256, 0, stream>>>(bufA, Wc2, bufB);
    k_gather<0><<<TOTALN / 4, 256, 0, stream>>>(bufB, bufA, rowptr, csr_src, csr_w, dinv, bc2);
    // layer 3 (no relu; bias folded into pool stage 2)
    k_mm128<<<500, 256, 0, stream>>>(bufA, Wc3, bufB);
    k_gather<1><<<TOTALN / 4, 256, 0, stream>>>(bufB, bufA, rowptr, csr_src, csr_w, dinv, nullptr);
    k_pool1<<<NB * PCH, 256, 0, stream>>>(bufA, pp);
    k_pool2<<<(NB * 128 + 255) / 256, 256, 0, stream>>>(pp, bc3, hg);

    // hypernetwork + compute_q
    k_w1<<<NH * W1CH, 512, 0, stream>>>(hg, Wg1, bg1, act, p1);
    k_red1<<<96, 256, 0, stream>>>(p1, h1);
    k_w2<<<NH * Dh, 256, 0, stream>>>(hg, Wg2, bg2, h1, p2);
    k_red2<<<24, 256, 0, stream>>>(p2, h2);
    k_out<<<NB, 192, 0, stream>>>(hg, Wg3, bg3, h2, out);
}

// Round 8
// 391.769 us; speedup vs baseline: 1.2069x; 1.0243x over previous
//
#include <hip/hip_runtime.h>
#include <hip/hip_bf16.h>
#include <math.h>

#define NB 32          // graphs
#define N_PER 1000
#define TOTALN 32000
#define NE 512000
#define HID 128
#define Dh 64
#define NH 3
#define EPSV 1e-6f
#define PCH 25         // pool chunks per graph (40 nodes each)
#define W1CH 250       // k_w1 chunks (4 n's each)

__device__ __forceinline__ float softplusf(float x) {
    return fmaxf(x, 0.0f) + log1pf(expf(-fabsf(x)));
}

__global__ __launch_bounds__(256) void k_init_deg(float* deg) {
    int i = blockIdx.x * 256 + threadIdx.x;
    if (i < TOTALN) deg[i] = 1.0f;   // self loop
}

__global__ __launch_bounds__(256) void k_deg(const int* __restrict__ ei, float* deg) {
    int e = blockIdx.x * 256 + threadIdx.x;
    if (e < NE) atomicAdd(&deg[ei[NE + e]], 1.0f);
}

// dinv = rsqrt(deg); cnt = (int)deg - 1 (edges only, self-loop excluded)
__global__ __launch_bounds__(256) void k_prep(float* __restrict__ d, int* __restrict__ cnt) {
    int i = blockIdx.x * 256 + threadIdx.x;
    if (i < TOTALN) {
        float v = d[i];
        cnt[i] = (int)v - 1;
        d[i] = rsqrtf(v);
    }
}

// exclusive scan of cnt[32000] -> rowptr; 125 blocks x 256
__global__ __launch_bounds__(256) void k_scan_block(const int* __restrict__ cnt,
                                                    int* __restrict__ rowptr,
                                                    int* __restrict__ bsum) {
    __shared__ int sh[256];
    int t = threadIdx.x;
    int i = blockIdx.x * 256 + t;
    int v = cnt[i];
    sh[t] = v;
    __syncthreads();
    for (int off = 1; off < 256; off <<= 1) {
        int add = (t >= off) ? sh[t - off] : 0;
        __syncthreads();
        sh[t] += add;
        __syncthreads();
    }
    rowptr[i] = sh[t] - v;   // exclusive within block
    if (t == 255) bsum[blockIdx.x] = sh[255];
}

__global__ void k_scan_tot(int* __restrict__ bsum) {
    if (threadIdx.x == 0) {
        int run = 0;
        for (int i = 0; i < 125; ++i) { int t = bsum[i]; bsum[i] = run; run += t; }
    }
}

__global__ __launch_bounds__(256) void k_scan_add(int* __restrict__ rowptr,
                                                  const int* __restrict__ bsum,
                                                  int* __restrict__ cursor) {
    int i = blockIdx.x * 256 + threadIdx.x;
    int v = rowptr[i] + bsum[blockIdx.x];
    rowptr[i] = v;
    cursor[i] = v;
    if (i == 0) rowptr[TOTALN] = NE;
}

__global__ __launch_bounds__(256) void k_fill(const int* __restrict__ ei,
                                              const float* __restrict__ dinv,
                                              int* __restrict__ cursor,
                                              int* __restrict__ csr_src,
                                              float* __restrict__ csr_w) {
    int e = blockIdx.x * 256 + threadIdx.x;
    if (e < NE) {
        int s = ei[e], d = ei[NE + e];
        int pos = atomicAdd(&cursor[d], 1);
        csr_src[pos] = s;
        csr_w[pos] = dinv[s] * dinv[d];
    }
}

// Y[rows x 128] = X[rows x 128] @ W[128 x 128]; 64 rows per block
__global__ __launch_bounds__(256) void k_mm128(const float* __restrict__ X,
                                               const float* __restrict__ W,
                                               float* __restrict__ Y) {
    __shared__ float xs[64][128];
    __shared__ float ws[32][128];
    int tid = threadIdx.x;
    int row0 = blockIdx.x * 64;
    int c = tid & 127, rp = tid >> 7;
    for (int i = 0; i < 32; ++i) {
        int idx = tid + i * 256;
        xs[idx >> 7][idx & 127] = X[(row0 + (idx >> 7)) * 128 + (idx & 127)];
    }
    float acc[32];
#pragma unroll
    for (int i = 0; i < 32; ++i) acc[i] = 0.f;
    for (int kc = 0; kc < 4; ++kc) {
        __syncthreads();
        for (int i = 0; i < 16; ++i) {
            int idx = tid + i * 256;
            ws[idx >> 7][idx & 127] = W[(kc * 32 + (idx >> 7)) * 128 + (idx & 127)];
        }
        __syncthreads();
#pragma unroll 4
        for (int k = 0; k < 32; ++k) {
            float w = ws[k][c];
#pragma unroll
            for (int i = 0; i < 32; ++i)
                acc[i] += xs[rp * 32 + i][kc * 32 + k] * w;
        }
    }
#pragma unroll
    for (int i = 0; i < 32; ++i)
        Y[(row0 + rp * 32 + i) * 128 + c] = acc[i];
}

// CSR gather: 1 wave per node, float2 per lane, 4-deep edge ILP.
// MODE 0: +bias,relu ; MODE 1: plain
template<int MODE>
__global__ __launch_bounds__(256) void k_gather(const float* __restrict__ feat,
                                                float* __restrict__ out,
                                                const int* __restrict__ rowptr,
                                                const int* __restrict__ csr_src,
                                                const float* __restrict__ csr_w,
                                                const float* __restrict__ dinv,
                                                const float* __restrict__ bias) {
    int wid = threadIdx.x >> 6, lane = threadIdx.x & 63;
    int v = blockIdx.x * 4 + wid;
    const float2* f2 = (const float2*)feat;
    float dv = dinv[v];
    float2 self = f2[v * 64 + lane];
    float acc0 = self.x * dv * dv, acc1 = self.y * dv * dv;
    int e = rowptr[v], e1 = rowptr[v + 1];
    for (; e + 4 <= e1; e += 4) {
        int s0 = csr_src[e], s1 = csr_src[e + 1], s2 = csr_src[e + 2], s3 = csr_src[e + 3];
        float w0 = csr_w[e], w1 = csr_w[e + 1], w2 = csr_w[e + 2], w3 = csr_w[e + 3];
        float2 f0 = f2[s0 * 64 + lane];
        float2 f1 = f2[s1 * 64 + lane];
        float2 fa = f2[s2 * 64 + lane];
        float2 fb = f2[s3 * 64 + lane];
        acc0 += f0.x * w0 + f1.x * w1 + fa.x * w2 + fb.x * w3;
        acc1 += f0.y * w0 + f1.y * w1 + fa.y * w2 + fb.y * w3;
    }
    for (; e < e1; ++e) {
        int s = csr_src[e];
        float w = csr_w[e];
        float2 f = f2[s * 64 + lane];
        acc0 += f.x * w;
        acc1 += f.y * w;
    }
    if (MODE == 0) {
        int c = lane * 2;
        acc0 = fmaxf(acc0 + bias[c], 0.f);
        acc1 = fmaxf(acc1 + bias[c + 1], 0.f);
    }
    ((float2*)out)[v * 64 + lane] = make_float2(acc0, acc1);
}

// pool stage 1: block = (graph b, chunk of 40 nodes) -> partial sums
__global__ __launch_bounds__(256) void k_pool1(const float* __restrict__ A,
                                               float* __restrict__ pp) {
    __shared__ float sh[256];
    int b = blockIdx.x / PCH, ch = blockIdx.x % PCH;
    int c = threadIdx.x & 127, half = threadIdx.x >> 7;
    float acc = 0.f;
    int n0 = ch * 40;
#pragma unroll 4
    for (int j = half; j < 40; j += 2)
        acc += A[(b * N_PER + n0 + j) * 128 + c];
    sh[threadIdx.x] = acc;
    __syncthreads();
    if (threadIdx.x < 128)
        pp[blockIdx.x * 128 + c] = sh[c] + sh[128 + c];
}

// pool stage 2: reduce 25 partials, mean + layer-3 bias; writes hg AND hgT
__global__ __launch_bounds__(256) void k_pool2(const float* __restrict__ pp,
                                               const float* __restrict__ bias,
                                               float* __restrict__ hg,
                                               float* __restrict__ hgT) {
    int i = blockIdx.x * 256 + threadIdx.x;   // b*128 + c
    if (i >= NB * 128) return;
    int b = i >> 7, c = i & 127;
    float s = 0.f;
#pragma unroll
    for (int ch = 0; ch < PCH; ++ch)
        s += pp[(b * PCH + ch) * 128 + c];
    float v = s * (1.0f / N_PER) + bias[c];
    hg[i] = v;
    hgT[c * NB + b] = v;   // transposed copy for k_w1's contiguous s_loads
}

// k_w1: block = (head h, chunk of 4 n's); 512 threads = 8 waves = (nsub, khalf).
// Each wave: 64-k partial dot for all 32 graphs of one n (lane = d).
// Broadcast operand read from hgT[k][b] -> 32 CONTIGUOUS floats per k
// (two s_load_dwordx16 instead of 32 strided s_load_dwordx4; fits SGPR budget,
// one lgkmcnt per k). k0 via readfirstlane keeps everything provably uniform.
__global__ __launch_bounds__(512) void k_w1(const float* __restrict__ hgT,
                                            const float* __restrict__ Wg1,
                                            const float* __restrict__ bg1,
                                            const float* __restrict__ actions,
                                            float* __restrict__ p1) {
    __shared__ float red[4][32][64];   // [nsub][b][d]
    int h = blockIdx.x / W1CH, chunk = blockIdx.x % W1CH;
    int tid = threadIdx.x;
    int wv = tid >> 6, d = tid & 63;
    int khalf = wv & 1, nsub = wv >> 1;
    int n = chunk * 4 + nsub;
    const long KS = (long)NH * N_PER * Dh;   // 192000
    long col = (long)(h * N_PER + n) * Dh + d;
    const float* Wp = Wg1 + col;
    int k0 = __builtin_amdgcn_readfirstlane(khalf * 64);   // force SGPR-uniform
    float acc[32];
#pragma unroll
    for (int b = 0; b < 32; ++b) acc[b] = 0.f;
    float4 wc;
    wc.x = Wp[(long)(k0 + 0) * KS];
    wc.y = Wp[(long)(k0 + 1) * KS];
    wc.z = Wp[(long)(k0 + 2) * KS];
    wc.w = Wp[(long)(k0 + 3) * KS];
    for (int kk = 0; kk < 64; kk += 4) {
        int k = k0 + kk;
        float4 wn = make_float4(0.f, 0.f, 0.f, 0.f);
        if (kk + 4 < 64) {
            wn.x = Wp[(long)(k + 4) * KS];
            wn.y = Wp[(long)(k + 5) * KS];
            wn.z = Wp[(long)(k + 6) * KS];
            wn.w = Wp[(long)(k + 7) * KS];
        }
#pragma unroll
        for (int kq = 0; kq < 4; ++kq) {
            float w = (kq == 0) ? wc.x : (kq == 1) ? wc.y : (kq == 2) ? wc.z : wc.w;
            const float* hp = hgT + (k + kq) * NB;   // uniform, contiguous 32 floats
#pragma unroll
            for (int b = 0; b < 32; ++b)
                acc[b] = fmaf(hp[b], w, acc[b]);
        }
        wc = wn;
    }
    // combine k-halves (pre-softplus)
    if (khalf == 0) {
#pragma unroll
        for (int b = 0; b < 32; ++b) red[nsub][b][d] = acc[b];
    }
    __syncthreads();
    if (khalf == 1) {
#pragma unroll
        for (int b = 0; b < 32; ++b) red[nsub][b][d] += acc[b];
    }
    __syncthreads();
    // softplus + action (one wave per n)
    if (khalf == 0) {
        float bgv = bg1[col];
#pragma unroll
        for (int b = 0; b < 32; ++b)
            red[nsub][b][d] = actions[b * N_PER + n] * softplusf(red[nsub][b][d] + bgv);
    }
    __syncthreads();
    // parallel n-reduction: 512 threads x 4 outputs each
    const float* rf = &red[0][0][0];
    float* po = p1 + (long)(chunk * NH + h) * 2048;
#pragma unroll
    for (int j = 0; j < 4; ++j) {
        int o = j * 512 + tid;
        po[o] = rf[o] + rf[2048 + o] + rf[4096 + o] + rf[6144 + o];
    }
}

// block = (b,h): 96 blocks; thread = (part, d); 4-way chunk split + LDS finish
__global__ __launch_bounds__(256) void k_red1(const float* __restrict__ p1,
                                              float* __restrict__ h1) {
    __shared__ float sh[4][64];
    int b = blockIdx.x / 3, h = blockIdx.x % 3;
    int part = threadIdx.x >> 6, d = threadIdx.x & 63;
    float s = 0.f;
    for (int ch = part; ch < W1CH; ch += 4)
        s += p1[(long)(ch * 3 + h) * 2048 + b * 64 + d];
    if (part) sh[part][d] = s;
    __syncthreads();
    if (part == 0)
        h1[(b * 3 + h) * 64 + d] = sqrtf(fmaxf(s + sh[1][d] + sh[2][d] + sh[3][d], 0.f) + EPSV);
}

// block = (h*64+d); writes p2[hd][b][e]
__global__ __launch_bounds__(256) void k_w2(const float* __restrict__ hg,
                                            const float* __restrict__ Wg2,
                                            const float* __restrict__ bg2,
                                            const float* __restrict__ h1,
                                            float* __restrict__ p2) {
    __shared__ float hgs[32][128];
    __shared__ float wt[128][64];
    __shared__ float h1s[32];
    int hd = blockIdx.x;  // h*64 + d
    int tid = threadIdx.x;
    for (int i = 0; i < 16; ++i) {
        int idx = tid + i * 256;
        hgs[idx >> 7][idx & 127] = hg[idx];
    }
    long base = (long)hd * 64;
    for (int i = 0; i < 32; ++i) {
        int idx = tid + i * 256;
        wt[idx >> 6][idx & 63] = Wg2[(long)(idx >> 6) * (NH * Dh * Dh) + base + (idx & 63)];
    }
    int h = hd >> 6, d = hd & 63;
    if (tid < 32) h1s[tid] = h1[tid * (NH * Dh) + h * Dh + d];
    __syncthreads();
    int e = tid & 63, bq = tid >> 6;
    float bgv = bg2[base + e];
    float dot[8];
#pragma unroll
    for (int bi = 0; bi < 8; ++bi) dot[bi] = 0.f;
    for (int k = 0; k < 128; ++k) {
        float w = wt[k][e];
#pragma unroll
        for (int bi = 0; bi < 8; ++bi)
            dot[bi] += hgs[bq * 8 + bi][k] * w;
    }
    float* po = p2 + (long)hd * (32 * 64);
#pragma unroll
    for (int bi = 0; bi < 8; ++bi) {
        int b = bq * 8 + bi;
        po[b * 64 + e] = softplusf(dot[bi] + bgv) * h1s[b];
    }
}

__global__ __launch_bounds__(256) void k_red2(const float* __restrict__ p2,
                                              float* __restrict__ h2) {
    int o = blockIdx.x * 256 + threadIdx.x;  // b*192 + h*64 + e
    if (o >= 32 * 192) return;
    int bh = o >> 6;
    int h = bh % 3, b = bh / 3;
    int e = o & 63;
    float s = 0.f;
    for (int d = 0; d < 64; ++d)
        s += p2[(h * 64 + d) * 2048 + b * 64 + e];
    h2[o] = log1pf(fmaxf(s, 0.f));   // SafeLog
}

__global__ __launch_bounds__(192) void k_out(const float* __restrict__ hg,
                                             const float* __restrict__ Wg3,
                                             const float* __restrict__ bg3,
                                             const float* __restrict__ h2,
                                             float* __restrict__ out) {
    __shared__ float hgb[128];
    __shared__ float hres[NH];
    int b = blockIdx.x, tid = threadIdx.x;
    if (tid < 128) hgb[tid] = hg[b * 128 + tid];
    __syncthreads();
    int h = tid / 64, e = tid & 63;
    int c = h * 64 + e;
    float dot = 0.f;
    for (int k = 0; k < 128; ++k)
        dot += hgb[k] * Wg3[k * (NH * Dh) + c];
    float v = softplusf(dot + bg3[c]) * h2[b * 192 + c];
    for (int off = 32; off; off >>= 1)
        v += __shfl_down(v, off, 64);
    if (e == 0) hres[h] = v;
    __syncthreads();
    if (tid == 0) out[b] = fminf(fminf(hres[0], hres[1]), hres[2]);
}

extern "C" void kernel_launch(void* const* d_in, const int* in_sizes, int n_in,
                              void* d_out, int out_size, void* d_ws, size_t ws_size,
                              hipStream_t stream) {
    const float* x   = (const float*)d_in[0];
    const int*   ei  = (const int*)d_in[1];
    const float* act = (const float*)d_in[3];
    const float* Wc1 = (const float*)d_in[4];
    const float* bc1 = (const float*)d_in[5];
    const float* Wc2 = (const float*)d_in[6];
    const float* bc2 = (const float*)d_in[7];
    const float* Wc3 = (const float*)d_in[8];
    const float* bc3 = (const float*)d_in[9];
    const float* Wg1 = (const float*)d_in[10];
    const float* bg1 = (const float*)d_in[11];
    const float* Wg2 = (const float*)d_in[12];
    const float* bg2 = (const float*)d_in[13];
    const float* Wg3 = (const float*)d_in[14];
    const float* bg3 = (const float*)d_in[15];
    float* out = (float*)d_out;

    float* ws   = (float*)d_ws;
    float* dinv = ws;                               // 32000
    float* bufA = dinv + TOTALN;                    // 4.096M
    float* bufB = bufA + (long)TOTALN * 128;        // 4.096M
    float* hg   = bufB + (long)TOTALN * 128;        // 4096
    float* h1   = hg + 32 * 128;                    // 6144
    float* h2   = h1 + 32 * 192;                    // 6144
    float* csr_w = h2 + 32 * 192;                   // 512000
    float* pp   = csr_w + NE;                       // 102400
    float* hgT  = pp + NB * PCH * 128;              // 4096
    int* cnt    = (int*)(hgT + 128 * NB);           // 32000
    int* rowptr = cnt + TOTALN;                     // 32001
    int* cursor = rowptr + TOTALN + 1;              // 32000
    int* bsum   = cursor + TOTALN;                  // 128
    int* csr_src= bsum + 128;                       // 512000
    // aliases: bufB free after last gather; bufA free after pool1
    float* p1   = bufB;                             // 250*3*2048 = 1.536M <= 4.096M
    float* p2   = bufA;                             // 64*3*2048  = 393216 <= 4.096M

    // degree + norm + CSR build
    k_init_deg<<<(TOTALN + 255) / 256, 256, 0, stream>>>(dinv);
    k_deg<<<NE / 256, 256, 0, stream>>>(ei, dinv);
    k_prep<<<(TOTALN + 255) / 256, 256, 0, stream>>>(dinv, cnt);
    k_scan_block<<<125, 256, 0, stream>>>(cnt, rowptr, bsum);
    k_scan_tot<<<1, 64, 0, stream>>>(bsum);
    k_scan_add<<<125, 256, 0, stream>>>(rowptr, bsum, cursor);
    k_fill<<<NE / 256, 256, 0, stream>>>(ei, dinv, cursor, csr_src, csr_w);

    // layer 1
    k_mm128<<<500, 256, 0, stream>>>(x, Wc1, bufB);
    k_gather<0><<<TOTALN / 4, 256, 0, stream>>>(bufB, bufA, rowptr, csr_src, csr_w, dinv, bc1);
    // layer 2
    k_mm128<<<500, 256, 0, stream>>>(bufA, Wc2, bufB);
    k_gather<0><<<TOTALN / 4, 256, 0, stream>>>(bufB, bufA, rowptr, csr_src, csr_w, dinv, bc2);
    // layer 3 (no relu; bias folded into pool stage 2)
    k_mm128<<<500, 256, 0, stream>>>(bufA, Wc3, bufB);
    k_gather<1><<<TOTALN / 4, 256, 0, stream>>>(bufB, bufA, rowptr, csr_src, csr_w, dinv, nullptr);
    k_pool1<<<NB * PCH, 256, 0, stream>>>(bufA, pp);
    k_pool2<<<(NB * 128 + 255) / 256, 256, 0, stream>>>(pp, bc3, hg, hgT);

    // hypernetwork + compute_q
    k_w1<<<NH * W1CH, 512, 0, stream>>>(hgT, Wg1, bg1, act, p1);
    k_red1<<<96, 256, 0, stream>>>(p1, h1);
    k_w2<<<NH * Dh, 256, 0, stream>>>(hg, Wg2, bg2, h1, p2);
    k_red2<<<24, 256, 0, stream>>>(p2, h2);
    k_out<<<NB, 192, 0, stream>>>(hg, Wg3, bg3, h2, out);
}

// Round 9
// 293.053 us; speedup vs baseline: 1.6135x; 1.3369x over previous
//
#include <hip/hip_runtime.h>
#include <hip/hip_bf16.h>
#include <math.h>

#define NB 32          // graphs
#define N_PER 1000
#define TOTALN 32000
#define NE 512000
#define HID 128
#define Dh 64
#define NH 3
#define EPSV 1e-6f
#define PCH 25         // pool chunks per graph (40 nodes each)
#define W1CH 250       // k_w1 chunks (4 n's each)

typedef __attribute__((ext_vector_type(8))) short bf16x8;
typedef __attribute__((ext_vector_type(4))) float f32x4;

__device__ __forceinline__ float softplusf(float x) {
    return fmaxf(x, 0.0f) + log1pf(expf(-fabsf(x)));
}
__device__ __forceinline__ unsigned short f2b(float f) {
    __hip_bfloat16 h = __float2bfloat16(f);
    return __builtin_bit_cast(unsigned short, h);
}
__device__ __forceinline__ float b2f(unsigned short u) {
    unsigned int x = ((unsigned int)u) << 16;
    return __builtin_bit_cast(float, x);
}

__global__ __launch_bounds__(256) void k_init_deg(float* deg) {
    int i = blockIdx.x * 256 + threadIdx.x;
    if (i < TOTALN) deg[i] = 1.0f;   // self loop
}

__global__ __launch_bounds__(256) void k_deg(const int* __restrict__ ei, float* deg) {
    int e = blockIdx.x * 256 + threadIdx.x;
    if (e < NE) atomicAdd(&deg[ei[NE + e]], 1.0f);
}

__global__ __launch_bounds__(256) void k_prep(float* __restrict__ d, int* __restrict__ cnt) {
    int i = blockIdx.x * 256 + threadIdx.x;
    if (i < TOTALN) {
        float v = d[i];
        cnt[i] = (int)v - 1;
        d[i] = rsqrtf(v);
    }
}

__global__ __launch_bounds__(256) void k_scan_block(const int* __restrict__ cnt,
                                                    int* __restrict__ rowptr,
                                                    int* __restrict__ bsum) {
    __shared__ int sh[256];
    int t = threadIdx.x;
    int i = blockIdx.x * 256 + t;
    int v = cnt[i];
    sh[t] = v;
    __syncthreads();
    for (int off = 1; off < 256; off <<= 1) {
        int add = (t >= off) ? sh[t - off] : 0;
        __syncthreads();
        sh[t] += add;
        __syncthreads();
    }
    rowptr[i] = sh[t] - v;
    if (t == 255) bsum[blockIdx.x] = sh[255];
}

__global__ void k_scan_tot(int* __restrict__ bsum) {
    if (threadIdx.x == 0) {
        int run = 0;
        for (int i = 0; i < 125; ++i) { int t = bsum[i]; bsum[i] = run; run += t; }
    }
}

__global__ __launch_bounds__(256) void k_scan_add(int* __restrict__ rowptr,
                                                  const int* __restrict__ bsum,
                                                  int* __restrict__ cursor) {
    int i = blockIdx.x * 256 + threadIdx.x;
    int v = rowptr[i] + bsum[blockIdx.x];
    rowptr[i] = v;
    cursor[i] = v;
    if (i == 0) rowptr[TOTALN] = NE;
}

__global__ __launch_bounds__(256) void k_fill(const int* __restrict__ ei,
                                              const float* __restrict__ dinv,
                                              int* __restrict__ cursor,
                                              int* __restrict__ csr_src,
                                              float* __restrict__ csr_w) {
    int e = blockIdx.x * 256 + threadIdx.x;
    if (e < NE) {
        int s = ei[e], d = ei[NE + e];
        int pos = atomicAdd(&cursor[d], 1);
        csr_src[pos] = s;
        csr_w[pos] = dinv[s] * dinv[d];
    }
}

// transpose+convert W[128][128] f32 -> Wt[c][k] bf16
__global__ __launch_bounds__(256) void k_wcvt(const float* __restrict__ W,
                                              unsigned short* __restrict__ Wt) {
    int i = blockIdx.x * 256 + threadIdx.x;   // 16384
    int k = i >> 7, c = i & 127;
    Wt[c * 128 + k] = f2b(W[i]);
}

// Y[32000 x 128](bf16) = X[32000 x 128] @ W ; MFMA 16x16x32 bf16, no LDS.
// wave = 16 rows; A frags per-lane from X rows; B frags per-lane from Wt (L1-hot).
// INF32: X is f32 (layer 1), else bf16.
template<int INF32>
__global__ __launch_bounds__(256) void k_mm(const void* __restrict__ Xv,
                                            const unsigned short* __restrict__ Wt,
                                            unsigned short* __restrict__ Y) {
    int tid = threadIdx.x;
    int wv = tid >> 6, l = tid & 63;
    int row0 = blockIdx.x * 64 + wv * 16;
    int r = l & 15, kc = l >> 4;          // A/B lane row(col), k-chunk
    bf16x8 a[4];
    if (INF32) {
        const float* X = (const float*)Xv;
#pragma unroll
        for (int ks = 0; ks < 4; ++ks) {
            const float* p = X + (long)(row0 + r) * 128 + ks * 32 + kc * 8;
            float4 f0 = *(const float4*)p;
            float4 f1 = *(const float4*)(p + 4);
            bf16x8 t;
            t[0] = (short)f2b(f0.x); t[1] = (short)f2b(f0.y);
            t[2] = (short)f2b(f0.z); t[3] = (short)f2b(f0.w);
            t[4] = (short)f2b(f1.x); t[5] = (short)f2b(f1.y);
            t[6] = (short)f2b(f1.z); t[7] = (short)f2b(f1.w);
            a[ks] = t;
        }
    } else {
        const unsigned short* X = (const unsigned short*)Xv;
#pragma unroll
        for (int ks = 0; ks < 4; ++ks)
            a[ks] = *(const bf16x8*)(X + (long)(row0 + r) * 128 + ks * 32 + kc * 8);
    }
    f32x4 acc[8];
#pragma unroll
    for (int nt = 0; nt < 8; ++nt) acc[nt] = (f32x4){0.f, 0.f, 0.f, 0.f};
#pragma unroll
    for (int ks = 0; ks < 4; ++ks) {
#pragma unroll
        for (int nt = 0; nt < 8; ++nt) {
            bf16x8 b = *(const bf16x8*)(Wt + (nt * 16 + r) * 128 + ks * 32 + kc * 8);
            acc[nt] = __builtin_amdgcn_mfma_f32_16x16x32_bf16(a[ks], b, acc[nt], 0, 0, 0);
        }
    }
    // C/D: col = lane&15 (=r), row = (lane>>4)*4 + j  [verified m89 mapping]
#pragma unroll
    for (int nt = 0; nt < 8; ++nt)
#pragma unroll
        for (int j = 0; j < 4; ++j)
            Y[(long)(row0 + kc * 4 + j) * 128 + nt * 16 + r] = f2b(acc[nt][j]);
}

// CSR gather on bf16 features: 1 wave per node, ushort2(4B) per lane, 4-deep ILP.
// MODE 0: +bias,relu ; MODE 1: plain
template<int MODE>
__global__ __launch_bounds__(256) void k_gather(const unsigned short* __restrict__ feat,
                                                unsigned short* __restrict__ out,
                                                const int* __restrict__ rowptr,
                                                const int* __restrict__ csr_src,
                                                const float* __restrict__ csr_w,
                                                const float* __restrict__ dinv,
                                                const float* __restrict__ bias) {
    int wid = threadIdx.x >> 6, lane = threadIdx.x & 63;
    int v = blockIdx.x * 4 + wid;
    const unsigned int* f2 = (const unsigned int*)feat;   // 2 bf16 per uint
    float dv = dinv[v];
    unsigned int sv = f2[v * 64 + lane];
    float acc0 = b2f((unsigned short)(sv & 0xffff)) * dv * dv;
    float acc1 = b2f((unsigned short)(sv >> 16)) * dv * dv;
    int e = rowptr[v], e1 = rowptr[v + 1];
    for (; e + 4 <= e1; e += 4) {
        int s0 = csr_src[e], s1 = csr_src[e + 1], s2 = csr_src[e + 2], s3 = csr_src[e + 3];
        float w0 = csr_w[e], w1 = csr_w[e + 1], w2 = csr_w[e + 2], w3 = csr_w[e + 3];
        unsigned int u0 = f2[s0 * 64 + lane];
        unsigned int u1 = f2[s1 * 64 + lane];
        unsigned int u2 = f2[s2 * 64 + lane];
        unsigned int u3 = f2[s3 * 64 + lane];
        acc0 += b2f((unsigned short)(u0 & 0xffff)) * w0 + b2f((unsigned short)(u1 & 0xffff)) * w1
              + b2f((unsigned short)(u2 & 0xffff)) * w2 + b2f((unsigned short)(u3 & 0xffff)) * w3;
        acc1 += b2f((unsigned short)(u0 >> 16)) * w0 + b2f((unsigned short)(u1 >> 16)) * w1
              + b2f((unsigned short)(u2 >> 16)) * w2 + b2f((unsigned short)(u3 >> 16)) * w3;
    }
    for (; e < e1; ++e) {
        int s = csr_src[e];
        float w = csr_w[e];
        unsigned int u = f2[s * 64 + lane];
        acc0 += b2f((unsigned short)(u & 0xffff)) * w;
        acc1 += b2f((unsigned short)(u >> 16)) * w;
    }
    if (MODE == 0) {
        int c = lane * 2;
        acc0 = fmaxf(acc0 + bias[c], 0.f);
        acc1 = fmaxf(acc1 + bias[c + 1], 0.f);
    }
    ((unsigned int*)out)[v * 64 + lane] =
        (unsigned int)f2b(acc0) | ((unsigned int)f2b(acc1) << 16);
}

// pool stage 1 (bf16 input): block = (graph b, chunk of 40 nodes)
__global__ __launch_bounds__(256) void k_pool1(const unsigned short* __restrict__ A,
                                               float* __restrict__ pp) {
    __shared__ float sh[256];
    int b = blockIdx.x / PCH, ch = blockIdx.x % PCH;
    int c = threadIdx.x & 127, half = threadIdx.x >> 7;
    float acc = 0.f;
    int n0 = ch * 40;
#pragma unroll 4
    for (int j = half; j < 40; j += 2)
        acc += b2f(A[(long)(b * N_PER + n0 + j) * 128 + c]);
    sh[threadIdx.x] = acc;
    __syncthreads();
    if (threadIdx.x < 128)
        pp[blockIdx.x * 128 + c] = sh[c] + sh[128 + c];
}

// pool stage 2: reduce 25 partials, mean + layer-3 bias; writes hg AND hgT
__global__ __launch_bounds__(256) void k_pool2(const float* __restrict__ pp,
                                               const float* __restrict__ bias,
                                               float* __restrict__ hg,
                                               float* __restrict__ hgT) {
    int i = blockIdx.x * 256 + threadIdx.x;
    if (i >= NB * 128) return;
    int b = i >> 7, c = i & 127;
    float s = 0.f;
#pragma unroll
    for (int ch = 0; ch < PCH; ++ch)
        s += pp[(b * PCH + ch) * 128 + c];
    float v = s * (1.0f / N_PER) + bias[c];
    hg[i] = v;
    hgT[c * NB + b] = v;
}

// k_w1: unchanged from R8 (contiguous hgT s_loads, readfirstlane-uniform k0)
__global__ __launch_bounds__(512) void k_w1(const float* __restrict__ hgT,
                                            const float* __restrict__ Wg1,
                                            const float* __restrict__ bg1,
                                            const float* __restrict__ actions,
                                            float* __restrict__ p1) {
    __shared__ float red[4][32][64];
    int h = blockIdx.x / W1CH, chunk = blockIdx.x % W1CH;
    int tid = threadIdx.x;
    int wv = tid >> 6, d = tid & 63;
    int khalf = wv & 1, nsub = wv >> 1;
    int n = chunk * 4 + nsub;
    const long KS = (long)NH * N_PER * Dh;
    long col = (long)(h * N_PER + n) * Dh + d;
    const float* Wp = Wg1 + col;
    int k0 = __builtin_amdgcn_readfirstlane(khalf * 64);
    float acc[32];
#pragma unroll
    for (int b = 0; b < 32; ++b) acc[b] = 0.f;
    float4 wc;
    wc.x = Wp[(long)(k0 + 0) * KS];
    wc.y = Wp[(long)(k0 + 1) * KS];
    wc.z = Wp[(long)(k0 + 2) * KS];
    wc.w = Wp[(long)(k0 + 3) * KS];
    for (int kk = 0; kk < 64; kk += 4) {
        int k = k0 + kk;
        float4 wn = make_float4(0.f, 0.f, 0.f, 0.f);
        if (kk + 4 < 64) {
            wn.x = Wp[(long)(k + 4) * KS];
            wn.y = Wp[(long)(k + 5) * KS];
            wn.z = Wp[(long)(k + 6) * KS];
            wn.w = Wp[(long)(k + 7) * KS];
        }
#pragma unroll
        for (int kq = 0; kq < 4; ++kq) {
            float w = (kq == 0) ? wc.x : (kq == 1) ? wc.y : (kq == 2) ? wc.z : wc.w;
            const float* hp = hgT + (k + kq) * NB;
#pragma unroll
            for (int b = 0; b < 32; ++b)
                acc[b] = fmaf(hp[b], w, acc[b]);
        }
        wc = wn;
    }
    if (khalf == 0) {
#pragma unroll
        for (int b = 0; b < 32; ++b) red[nsub][b][d] = acc[b];
    }
    __syncthreads();
    if (khalf == 1) {
#pragma unroll
        for (int b = 0; b < 32; ++b) red[nsub][b][d] += acc[b];
    }
    __syncthreads();
    if (khalf == 0) {
        float bgv = bg1[col];
#pragma unroll
        for (int b = 0; b < 32; ++b)
            red[nsub][b][d] = actions[b * N_PER + n] * softplusf(red[nsub][b][d] + bgv);
    }
    __syncthreads();
    const float* rf = &red[0][0][0];
    float* po = p1 + (long)(chunk * NH + h) * 2048;
#pragma unroll
    for (int j = 0; j < 4; ++j) {
        int o = j * 512 + tid;
        po[o] = rf[o] + rf[2048 + o] + rf[4096 + o] + rf[6144 + o];
    }
}

__global__ __launch_bounds__(256) void k_red1(const float* __restrict__ p1,
                                              float* __restrict__ h1) {
    __shared__ float sh[4][64];
    int b = blockIdx.x / 3, h = blockIdx.x % 3;
    int part = threadIdx.x >> 6, d = threadIdx.x & 63;
    float s = 0.f;
    for (int ch = part; ch < W1CH; ch += 4)
        s += p1[(long)(ch * 3 + h) * 2048 + b * 64 + d];
    if (part) sh[part][d] = s;
    __syncthreads();
    if (part == 0)
        h1[(b * 3 + h) * 64 + d] = sqrtf(fmaxf(s + sh[1][d] + sh[2][d] + sh[3][d], 0.f) + EPSV);
}

__global__ __launch_bounds__(256) void k_w2(const float* __restrict__ hg,
                                            const float* __restrict__ Wg2,
                                            const float* __restrict__ bg2,
                                            const float* __restrict__ h1,
                                            float* __restrict__ p2) {
    __shared__ float hgs[32][128];
    __shared__ float wt[128][64];
    __shared__ float h1s[32];
    int hd = blockIdx.x;
    int tid = threadIdx.x;
    for (int i = 0; i < 16; ++i) {
        int idx = tid + i * 256;
        hgs[idx >> 7][idx & 127] = hg[idx];
    }
    long base = (long)hd * 64;
    for (int i = 0; i < 32; ++i) {
        int idx = tid + i * 256;
        wt[idx >> 6][idx & 63] = Wg2[(long)(idx >> 6) * (NH * Dh * Dh) + base + (idx & 63)];
    }
    int h = hd >> 6, d = hd & 63;
    if (tid < 32) h1s[tid] = h1[tid * (NH * Dh) + h * Dh + d];
    __syncthreads();
    int e = tid & 63, bq = tid >> 6;
    float bgv = bg2[base + e];
    float dot[8];
#pragma unroll
    for (int bi = 0; bi < 8; ++bi) dot[bi] = 0.f;
    for (int k = 0; k < 128; ++k) {
        float w = wt[k][e];
#pragma unroll
        for (int bi = 0; bi < 8; ++bi)
            dot[bi] += hgs[bq * 8 + bi][k] * w;
    }
    float* po = p2 + (long)hd * (32 * 64);
#pragma unroll
    for (int bi = 0; bi < 8; ++bi) {
        int b = bq * 8 + bi;
        po[b * 64 + e] = softplusf(dot[bi] + bgv) * h1s[b];
    }
}

__global__ __launch_bounds__(256) void k_red2(const float* __restrict__ p2,
                                              float* __restrict__ h2) {
    int o = blockIdx.x * 256 + threadIdx.x;
    if (o >= 32 * 192) return;
    int bh = o >> 6;
    int h = bh % 3, b = bh / 3;
    int e = o & 63;
    float s = 0.f;
    for (int d = 0; d < 64; ++d)
        s += p2[(h * 64 + d) * 2048 + b * 64 + e];
    h2[o] = log1pf(fmaxf(s, 0.f));
}

__global__ __launch_bounds__(192) void k_out(const float* __restrict__ hg,
                                             const float* __restrict__ Wg3,
                                             const float* __restrict__ bg3,
                                             const float* __restrict__ h2,
                                             float* __restrict__ out) {
    __shared__ float hgb[128];
    __shared__ float hres[NH];
    int b = blockIdx.x, tid = threadIdx.x;
    if (tid < 128) hgb[tid] = hg[b * 128 + tid];
    __syncthreads();
    int h = tid / 64, e = tid & 63;
    int c = h * 64 + e;
    float dot = 0.f;
    for (int k = 0; k < 128; ++k)
        dot += hgb[k] * Wg3[k * (NH * Dh) + c];
    float v = softplusf(dot + bg3[c]) * h2[b * 192 + c];
    for (int off = 32; off; off >>= 1)
        v += __shfl_down(v, off, 64);
    if (e == 0) hres[h] = v;
    __syncthreads();
    if (tid == 0) out[b] = fminf(fminf(hres[0], hres[1]), hres[2]);
}

extern "C" void kernel_launch(void* const* d_in, const int* in_sizes, int n_in,
                              void* d_out, int out_size, void* d_ws, size_t ws_size,
                              hipStream_t stream) {
    const float* x   = (const float*)d_in[0];
    const int*   ei  = (const int*)d_in[1];
    const float* act = (const float*)d_in[3];
    const float* Wc1 = (const float*)d_in[4];
    const float* bc1 = (const float*)d_in[5];
    const float* Wc2 = (const float*)d_in[6];
    const float* bc2 = (const float*)d_in[7];
    const float* Wc3 = (const float*)d_in[8];
    const float* bc3 = (const float*)d_in[9];
    const float* Wg1 = (const float*)d_in[10];
    const float* bg1 = (const float*)d_in[11];
    const float* Wg2 = (const float*)d_in[12];
    const float* bg2 = (const float*)d_in[13];
    const float* Wg3 = (const float*)d_in[14];
    const float* bg3 = (const float*)d_in[15];
    float* out = (float*)d_out;

    float* ws   = (float*)d_ws;
    float* dinv = ws;                               // 32000
    float* bufA = dinv + TOTALN;                    // feat A (bf16 lives here)
    float* bufB = bufA + (long)TOTALN * 128;        // feat B / p1 alias
    float* hg   = bufB + (long)TOTALN * 128;        // 4096
    float* h1   = hg + 32 * 128;                    // 6144
    float* h2   = h1 + 32 * 192;                    // 6144
    float* csr_w = h2 + 32 * 192;                   // 512000
    float* pp   = csr_w + NE;                       // 102400
    float* hgT  = pp + NB * PCH * 128;              // 4096
    int* cnt    = (int*)(hgT + 128 * NB);           // 32000
    int* rowptr = cnt + TOTALN;                     // 32001 (+3 pad for 16B align)
    int* cursor = rowptr + TOTALN + 4;              // 32000
    int* bsum   = cursor + TOTALN;                  // 128
    int* csr_src= bsum + 128;                       // 512000
    unsigned short* Wt = (unsigned short*)(csr_src + NE);  // 16384 bf16 (32KB)
    unsigned short* fA = (unsigned short*)bufA;
    unsigned short* fB = (unsigned short*)bufB;
    float* p1   = bufB;                             // free after layer-3 gather
    float* p2   = bufA;                             // free after pool1

    // degree + norm + CSR build
    k_init_deg<<<(TOTALN + 255) / 256, 256, 0, stream>>>(dinv);
    k_deg<<<NE / 256, 256, 0, stream>>>(ei, dinv);
    k_prep<<<(TOTALN + 255) / 256, 256, 0, stream>>>(dinv, cnt);
    k_scan_block<<<125, 256, 0, stream>>>(cnt, rowptr, bsum);
    k_scan_tot<<<1, 64, 0, stream>>>(bsum);
    k_scan_add<<<125, 256, 0, stream>>>(rowptr, bsum, cursor);
    k_fill<<<NE / 256, 256, 0, stream>>>(ei, dinv, cursor, csr_src, csr_w);

    // layer 1 (x f32 -> bf16 MFMA)
    k_wcvt<<<64, 256, 0, stream>>>(Wc1, Wt);
    k_mm<1><<<500, 256, 0, stream>>>(x, Wt, fB);
    k_gather<0><<<TOTALN / 4, 256, 0, stream>>>(fB, fA, rowptr, csr_src, csr_w, dinv, bc1);
    // layer 2
    k_wcvt<<<64, 256, 0, stream>>>(Wc2, Wt);
    k_mm<0><<<500, 256, 0, stream>>>(fA, Wt, fB);
    k_gather<0><<<TOTALN / 4, 256, 0, stream>>>(fB, fA, rowptr, csr_src, csr_w, dinv, bc2);
    // layer 3 (no relu; bias folded into pool stage 2)
    k_wcvt<<<64, 256, 0, stream>>>(Wc3, Wt);
    k_mm<0><<<500, 256, 0, stream>>>(fA, Wt, fB);
    k_gather<1><<<TOTALN / 4, 256, 0, stream>>>(fB, fA, rowptr, csr_src, csr_w, dinv, nullptr);
    k_pool1<<<NB * PCH, 256, 0, stream>>>(fA, pp);
    k_pool2<<<(NB * 128 + 255) / 256, 256, 0, stream>>>(pp, bc3, hg, hgT);

    // hypernetwork + compute_q
    k_w1<<<NH * W1CH, 512, 0, stream>>>(hgT, Wg1, bg1, act, p1);
    k_red1<<<96, 256, 0, stream>>>(p1, h1);
    k_w2<<<NH * Dh, 256, 0, stream>>>(hg, Wg2, bg2, h1, p2);
    k_red2<<<24, 256, 0, stream>>>(p2, h2);
    k_out<<<NB, 192, 0, stream>>>(hg, Wg3, bg3, h2, out);
}